// Round 2
// baseline (923.687 us; speedup 1.0000x reference)
//
#include <hip/hip_runtime.h>
#include <hip/hip_bf16.h>

#define N_NODES 100000
#define E_EDGES 1600000
#define IN_C 128
#define HID_C 64
#define OUT_C 40

// ---------------------------------------------------------------- degree
__global__ void k_deg(const int* __restrict__ dst, float* __restrict__ deg) {
    int i = blockIdx.x * 256 + threadIdx.x;
    if (i < E_EDGES) atomicAdd(&deg[dst[i]], 1.0f);
}

// ---------------------------------------------------------------- GEMM1: h1l = x@Wl1, h1r = x@Wr1  (x f32 [N,128], W f32 [128,64])
// tile: 64 rows x 64 cols, block 256, thread = 4 rows x 4 cols
__global__ __launch_bounds__(256) void k_gemm1(const float* __restrict__ x,
                                               const float* __restrict__ Wl,
                                               const float* __restrict__ Wr,
                                               float* __restrict__ h1l,
                                               float* __restrict__ h1r) {
    __shared__ float xs[64 * 132];             // 64 rows x 128 f32, stride 132 (pad)
    const int t = threadIdx.x;
    const int row_base = blockIdx.x * 64;

    // stage x tile: 64 rows x 32 float4
    for (int i = t; i < 64 * 32; i += 256) {
        int row = i >> 5, seg = i & 31;
        int gr = row_base + row;
        float4 val = make_float4(0.f, 0.f, 0.f, 0.f);
        if (gr < N_NODES)
            val = *(const float4*)(x + (size_t)gr * IN_C + seg * 4);
        *(float4*)(xs + row * 132 + seg * 4) = val;
    }
    __syncthreads();

    const int c0 = (t & 15) * 4;
    const int r0 = (t >> 4) * 4;
    float accl[4][4] = {};
    float accr[4][4] = {};

#pragma unroll 4
    for (int k = 0; k < IN_C; ++k) {
        float4 wl4 = *(const float4*)(Wl + k * HID_C + c0);
        float4 wr4 = *(const float4*)(Wr + k * HID_C + c0);
        float wl[4] = {wl4.x, wl4.y, wl4.z, wl4.w};
        float wr[4] = {wr4.x, wr4.y, wr4.z, wr4.w};
        float xv[4];
#pragma unroll
        for (int r = 0; r < 4; ++r) xv[r] = xs[(r0 + r) * 132 + k];
#pragma unroll
        for (int r = 0; r < 4; ++r) {
#pragma unroll
            for (int j = 0; j < 4; ++j) {
                accl[r][j] = fmaf(xv[r], wl[j], accl[r][j]);
                accr[r][j] = fmaf(xv[r], wr[j], accr[r][j]);
            }
        }
    }

#pragma unroll
    for (int r = 0; r < 4; ++r) {
        int gr = row_base + r0 + r;
        if (gr < N_NODES) {
            *(float4*)(h1l + (size_t)gr * HID_C + c0) =
                make_float4(accl[r][0], accl[r][1], accl[r][2], accl[r][3]);
            *(float4*)(h1r + (size_t)gr * HID_C + c0) =
                make_float4(accr[r][0], accr[r][1], accr[r][2], accr[r][3]);
        }
    }
}

// ---------------------------------------------------------------- scatter1: agg1[dst] += h1l[src], 64 ch/edge
__global__ void k_scatter1(const int* __restrict__ ei, const float* __restrict__ h1l,
                           float* __restrict__ agg1) {
    unsigned int id = blockIdx.x * 256 + threadIdx.x;
    unsigned int e = id >> 6;
    int c = id & 63;
    int s = ei[e];
    int d = ei[E_EDGES + e];
    atomicAdd(&agg1[(size_t)d * HID_C + c], h1l[(size_t)s * HID_C + c]);
}

// ---------------------------------------------------------------- hid = relu(agg1/deg + h1r + b1)   (in-place into h1r)
__global__ void k_hid(float* __restrict__ h1r, const float* __restrict__ agg1,
                      const float* __restrict__ deg, const float* __restrict__ b1) {
    size_t i = (size_t)blockIdx.x * 256 + threadIdx.x;
    if (i >= (size_t)N_NODES * HID_C) return;
    int row = (int)(i >> 6);
    int c = (int)(i & 63);
    float inv = 1.0f / fmaxf(deg[row], 1.0f);
    float v = agg1[i] * inv + h1r[i] + b1[c];
    h1r[i] = fmaxf(v, 0.0f);
}

// ---------------------------------------------------------------- GEMM2: h2l = hid@Wl2, h2r = hid@Wr2 (hid f32 [N,64], W f32 [64,40])
// tile: 128 rows x 40 cols, block 320, thread = 4 rows x 4 cols
__global__ __launch_bounds__(320) void k_gemm2(const float* __restrict__ hid,
                                               const float* __restrict__ Wl,
                                               const float* __restrict__ Wr,
                                               float* __restrict__ h2l,
                                               float* __restrict__ h2r) {
    __shared__ float hs[128 * 65];             // 128 rows x 64, pad +1
    __shared__ float2 Wp[HID_C * OUT_C];       // (wl, wr) per [k][c]
    const int t = threadIdx.x;

    for (int i = t; i < HID_C * OUT_C; i += 320)
        Wp[i] = make_float2(Wl[i], Wr[i]);

    const int row_base = blockIdx.x * 128;
    for (int i = t; i < 128 * 64; i += 320) {
        int row = i >> 6, c = i & 63;
        int gr = row_base + row;
        hs[row * 65 + c] = (gr < N_NODES) ? hid[(size_t)gr * HID_C + c] : 0.0f;
    }
    __syncthreads();

    const int c0 = (t % 10) * 4;
    const int r0 = (t / 10) * 4;
    float accl[4][4] = {};
    float accr[4][4] = {};

#pragma unroll 4
    for (int k = 0; k < HID_C; ++k) {
        float4 wa = *(const float4*)&Wp[k * OUT_C + c0];       // wl[c0],wr[c0],wl[c0+1],wr[c0+1]
        float4 wb = *(const float4*)&Wp[k * OUT_C + c0 + 2];
        float wl[4] = {wa.x, wa.z, wb.x, wb.z};
        float wr[4] = {wa.y, wa.w, wb.y, wb.w};
#pragma unroll
        for (int r = 0; r < 4; ++r) {
            float xv = hs[(r0 + r) * 65 + k];
#pragma unroll
            for (int j = 0; j < 4; ++j) {
                accl[r][j] = fmaf(xv, wl[j], accl[r][j]);
                accr[r][j] = fmaf(xv, wr[j], accr[r][j]);
            }
        }
    }

#pragma unroll
    for (int r = 0; r < 4; ++r) {
        int gr = row_base + r0 + r;
        if (gr < N_NODES) {
            *(float4*)(h2l + (size_t)gr * OUT_C + c0) =
                make_float4(accl[r][0], accl[r][1], accl[r][2], accl[r][3]);
            *(float4*)(h2r + (size_t)gr * OUT_C + c0) =
                make_float4(accr[r][0], accr[r][1], accr[r][2], accr[r][3]);
        }
    }
}

// ---------------------------------------------------------------- scatter2: agg2[dst] += h2l[src], 40 ch/edge
__global__ void k_scatter2(const int* __restrict__ ei, const float* __restrict__ h2l,
                           float* __restrict__ agg2) {
    unsigned int id = blockIdx.x * 256 + threadIdx.x;
    unsigned int e = id / 40u;
    unsigned int c = id - e * 40u;
    int s = ei[e];
    int d = ei[E_EDGES + e];
    atomicAdd(&agg2[(size_t)d * OUT_C + c], h2l[(size_t)s * OUT_C + c]);
}

// ---------------------------------------------------------------- final: log_softmax(agg2/deg + h2r + b2), one wave per row
__global__ __launch_bounds__(256) void k_final(const float* __restrict__ agg2,
                                               const float* __restrict__ h2r,
                                               const float* __restrict__ deg,
                                               const float* __restrict__ b2,
                                               float* __restrict__ out) {
    int wave = (blockIdx.x * 256 + threadIdx.x) >> 6;
    int lane = threadIdx.x & 63;
    if (wave >= N_NODES) return;
    float inv = 1.0f / fmaxf(deg[wave], 1.0f);
    float v = -1e30f;
    if (lane < OUT_C)
        v = agg2[(size_t)wave * OUT_C + lane] * inv + h2r[(size_t)wave * OUT_C + lane] + b2[lane];
    float m = v;
#pragma unroll
    for (int off = 32; off > 0; off >>= 1)
        m = fmaxf(m, __shfl_xor(m, off));
    float ex = (lane < OUT_C) ? expf(v - m) : 0.0f;
    float s = ex;
#pragma unroll
    for (int off = 32; off > 0; off >>= 1)
        s += __shfl_xor(s, off);
    float res = v - m - logf(s);
    if (lane < OUT_C)
        out[(size_t)wave * OUT_C + lane] = res;
}

// ----------------------------------------------------------------
extern "C" void kernel_launch(void* const* d_in, const int* in_sizes, int n_in,
                              void* d_out, int out_size, void* d_ws, size_t ws_size,
                              hipStream_t stream) {
    const float* x   = (const float*)d_in[0];
    const int*   ei  = (const int*)d_in[1];
    const float* Wl1 = (const float*)d_in[2];
    const float* b1  = (const float*)d_in[3];
    const float* Wr1 = (const float*)d_in[4];
    const float* Wl2 = (const float*)d_in[5];
    const float* b2  = (const float*)d_in[6];
    const float* Wr2 = (const float*)d_in[7];

    // workspace layout (floats): deg | h1l | h1r(->hid) | agg1(->h2r) | agg2
    size_t need = (size_t)N_NODES * (1 + 3 * HID_C + OUT_C) * sizeof(float);
    if (ws_size < need) return;  // insufficient scratch -- bail rather than corrupt

    float* ws   = (float*)d_ws;
    float* deg  = ws;
    float* h1l  = ws + N_NODES;
    float* h1r  = h1l + (size_t)N_NODES * HID_C;   // becomes hid in-place
    float* agg1 = h1r + (size_t)N_NODES * HID_C;   // becomes h2r after consumption
    float* agg2 = agg1 + (size_t)N_NODES * HID_C;
    float* h2l  = h1l;    // reuse: h1l consumed by scatter1 before gemm2
    float* h2r  = agg1;   // reuse: agg1 consumed by k_hid before gemm2

    hipMemsetAsync(deg, 0, N_NODES * sizeof(float), stream);
    hipMemsetAsync(agg1, 0, (size_t)N_NODES * HID_C * sizeof(float), stream);
    hipMemsetAsync(agg2, 0, (size_t)N_NODES * OUT_C * sizeof(float), stream);

    k_deg<<<(E_EDGES + 255) / 256, 256, 0, stream>>>(ei + E_EDGES, deg);
    k_gemm1<<<(N_NODES + 63) / 64, 256, 0, stream>>>(x, Wl1, Wr1, h1l, h1r);
    k_scatter1<<<(E_EDGES / 256) * 64, 256, 0, stream>>>(ei, h1l, agg1);
    k_hid<<<(N_NODES * HID_C) / 256, 256, 0, stream>>>(h1r, agg1, deg, b1);
    k_gemm2<<<(N_NODES + 127) / 128, 320, 0, stream>>>(h1r, Wl2, Wr2, h2l, h2r);
    k_scatter2<<<(E_EDGES / 256) * 40, 256, 0, stream>>>(ei, h2l, agg2);
    k_final<<<(N_NODES + 3) / 4, 256, 0, stream>>>(agg2, h2r, deg, b2, (float*)d_out);
}

// Round 3
// 510.017 us; speedup vs baseline: 1.8111x; 1.8111x over previous
//
#include <hip/hip_runtime.h>
#include <hip/hip_bf16.h>

#define N_NODES 100000
#define E_EDGES 1600000
#define IN_C 128
#define HID_C 64
#define OUT_C 40
#define NB 391  // ceil(N_NODES/256)

// ---------------------------------------------------------------- in-degree histogram (int)
__global__ void k_hist(const int* __restrict__ dst, int* __restrict__ hist) {
    int i = blockIdx.x * 256 + threadIdx.x;
    if (i < E_EDGES) atomicAdd(&hist[dst[i]], 1);
}

// ---------------------------------------------------------------- scan A: per-block sums
__global__ __launch_bounds__(256) void k_scanA(const int* __restrict__ hist, int* __restrict__ bsum) {
    __shared__ int tmp[256];
    int i = blockIdx.x * 256 + threadIdx.x;
    int v = (i < N_NODES) ? hist[i] : 0;
    tmp[threadIdx.x] = v;
    __syncthreads();
    for (int off = 128; off > 0; off >>= 1) {
        if (threadIdx.x < off) tmp[threadIdx.x] += tmp[threadIdx.x + off];
        __syncthreads();
    }
    if (threadIdx.x == 0) bsum[blockIdx.x] = tmp[0];
}

// ---------------------------------------------------------------- scan B: exclusive scan of block sums (1 block)
__global__ __launch_bounds__(512) void k_scanB(const int* __restrict__ bsum, int* __restrict__ boff,
                                               int* __restrict__ rowptr) {
    __shared__ int tmp[512];
    int t = threadIdx.x;
    int v = (t < NB) ? bsum[t] : 0;
    tmp[t] = v;
    __syncthreads();
    for (int off = 1; off < 512; off <<= 1) {
        int a = (t >= off) ? tmp[t - off] : 0;
        __syncthreads();
        tmp[t] += a;
        __syncthreads();
    }
    if (t < NB) boff[t] = tmp[t] - v;   // exclusive
    if (t == 0) rowptr[N_NODES] = E_EDGES;
}

// ---------------------------------------------------------------- scan C: rowptr[i] = boff[b] + exclusive-in-block
__global__ __launch_bounds__(256) void k_scanC(const int* __restrict__ hist, const int* __restrict__ boff,
                                               int* __restrict__ rowptr) {
    __shared__ int tmp[256];
    int i = blockIdx.x * 256 + threadIdx.x;
    int t = threadIdx.x;
    int v = (i < N_NODES) ? hist[i] : 0;
    tmp[t] = v;
    __syncthreads();
    for (int off = 1; off < 256; off <<= 1) {
        int a = (t >= off) ? tmp[t - off] : 0;
        __syncthreads();
        tmp[t] += a;
        __syncthreads();
    }
    if (i < N_NODES) rowptr[i] = boff[blockIdx.x] + tmp[t] - v;
}

// ---------------------------------------------------------------- fill CSR: csr[rowptr[d] + pos] = s
__global__ void k_fill(const int* __restrict__ ei, const int* __restrict__ rowptr,
                       int* __restrict__ cursor, int* __restrict__ csr) {
    int i = blockIdx.x * 256 + threadIdx.x;
    if (i >= E_EDGES) return;
    int s = ei[i];
    int d = ei[E_EDGES + i];
    int pos = atomicAdd(&cursor[d], 1);
    csr[rowptr[d] + pos] = s;
}

// ---------------------------------------------------------------- GEMM1: h1l = x@Wl1, h1r = x@Wr1  (f32)
__global__ __launch_bounds__(256) void k_gemm1(const float* __restrict__ x,
                                               const float* __restrict__ Wl,
                                               const float* __restrict__ Wr,
                                               float* __restrict__ h1l,
                                               float* __restrict__ h1r) {
    __shared__ float xs[64 * 132];
    const int t = threadIdx.x;
    const int row_base = blockIdx.x * 64;

    for (int i = t; i < 64 * 32; i += 256) {
        int row = i >> 5, seg = i & 31;
        int gr = row_base + row;
        float4 val = make_float4(0.f, 0.f, 0.f, 0.f);
        if (gr < N_NODES)
            val = *(const float4*)(x + (size_t)gr * IN_C + seg * 4);
        *(float4*)(xs + row * 132 + seg * 4) = val;
    }
    __syncthreads();

    const int c0 = (t & 15) * 4;
    const int r0 = (t >> 4) * 4;
    float accl[4][4] = {};
    float accr[4][4] = {};

#pragma unroll 4
    for (int k = 0; k < IN_C; ++k) {
        float4 wl4 = *(const float4*)(Wl + k * HID_C + c0);
        float4 wr4 = *(const float4*)(Wr + k * HID_C + c0);
        float wl[4] = {wl4.x, wl4.y, wl4.z, wl4.w};
        float wr[4] = {wr4.x, wr4.y, wr4.z, wr4.w};
        float xv[4];
#pragma unroll
        for (int r = 0; r < 4; ++r) xv[r] = xs[(r0 + r) * 132 + k];
#pragma unroll
        for (int r = 0; r < 4; ++r) {
#pragma unroll
            for (int j = 0; j < 4; ++j) {
                accl[r][j] = fmaf(xv[r], wl[j], accl[r][j]);
                accr[r][j] = fmaf(xv[r], wr[j], accr[r][j]);
            }
        }
    }

#pragma unroll
    for (int r = 0; r < 4; ++r) {
        int gr = row_base + r0 + r;
        if (gr < N_NODES) {
            *(float4*)(h1l + (size_t)gr * HID_C + c0) =
                make_float4(accl[r][0], accl[r][1], accl[r][2], accl[r][3]);
            *(float4*)(h1r + (size_t)gr * HID_C + c0) =
                make_float4(accr[r][0], accr[r][1], accr[r][2], accr[r][3]);
        }
    }
}

// ---------------------------------------------------------------- agg1 (gather) fused with relu(mean + root + b1)
// one wave per dst row, lane = channel; writes hid in-place into h1r
__global__ __launch_bounds__(256) void k_agg1(const int* __restrict__ rowptr, const int* __restrict__ csr,
                                              const float* __restrict__ h1l, float* __restrict__ h1r,
                                              const float* __restrict__ b1) {
    int wave = (blockIdx.x * 256 + threadIdx.x) >> 6;
    int lane = threadIdx.x & 63;
    if (wave >= N_NODES) return;
    int start = rowptr[wave];
    int end = rowptr[wave + 1];
    float acc = 0.0f;
    int e = start;
    for (; e + 4 <= end; e += 4) {
        int s0 = csr[e], s1 = csr[e + 1], s2 = csr[e + 2], s3 = csr[e + 3];
        float v0 = h1l[(size_t)s0 * HID_C + lane];
        float v1 = h1l[(size_t)s1 * HID_C + lane];
        float v2 = h1l[(size_t)s2 * HID_C + lane];
        float v3 = h1l[(size_t)s3 * HID_C + lane];
        acc += (v0 + v1) + (v2 + v3);
    }
    for (; e < end; ++e)
        acc += h1l[(size_t)csr[e] * HID_C + lane];
    float deg = (float)(end - start);
    float mean = acc / fmaxf(deg, 1.0f);
    size_t idx = (size_t)wave * HID_C + lane;
    float v = mean + h1r[idx] + b1[lane];
    h1r[idx] = fmaxf(v, 0.0f);
}

// ---------------------------------------------------------------- GEMM2: h2l = hid@Wl2, h2r = hid@Wr2
__global__ __launch_bounds__(320) void k_gemm2(const float* __restrict__ hid,
                                               const float* __restrict__ Wl,
                                               const float* __restrict__ Wr,
                                               float* __restrict__ h2l,
                                               float* __restrict__ h2r) {
    __shared__ float hs[128 * 65];
    __shared__ float2 Wp[HID_C * OUT_C];
    const int t = threadIdx.x;

    for (int i = t; i < HID_C * OUT_C; i += 320)
        Wp[i] = make_float2(Wl[i], Wr[i]);

    const int row_base = blockIdx.x * 128;
    for (int i = t; i < 128 * 64; i += 320) {
        int row = i >> 6, c = i & 63;
        int gr = row_base + row;
        hs[row * 65 + c] = (gr < N_NODES) ? hid[(size_t)gr * HID_C + c] : 0.0f;
    }
    __syncthreads();

    const int c0 = (t % 10) * 4;
    const int r0 = (t / 10) * 4;
    float accl[4][4] = {};
    float accr[4][4] = {};

#pragma unroll 4
    for (int k = 0; k < HID_C; ++k) {
        float4 wa = *(const float4*)&Wp[k * OUT_C + c0];
        float4 wb = *(const float4*)&Wp[k * OUT_C + c0 + 2];
        float wl[4] = {wa.x, wa.z, wb.x, wb.z};
        float wr[4] = {wa.y, wa.w, wb.y, wb.w};
#pragma unroll
        for (int r = 0; r < 4; ++r) {
            float xv = hs[(r0 + r) * 65 + k];
#pragma unroll
            for (int j = 0; j < 4; ++j) {
                accl[r][j] = fmaf(xv, wl[j], accl[r][j]);
                accr[r][j] = fmaf(xv, wr[j], accr[r][j]);
            }
        }
    }

#pragma unroll
    for (int r = 0; r < 4; ++r) {
        int gr = row_base + r0 + r;
        if (gr < N_NODES) {
            *(float4*)(h2l + (size_t)gr * OUT_C + c0) =
                make_float4(accl[r][0], accl[r][1], accl[r][2], accl[r][3]);
            *(float4*)(h2r + (size_t)gr * OUT_C + c0) =
                make_float4(accr[r][0], accr[r][1], accr[r][2], accr[r][3]);
        }
    }
}

// ---------------------------------------------------------------- agg2 (gather) fused with log_softmax(mean + root + b2)
// one wave per dst row, lanes 0..39 = channels
__global__ __launch_bounds__(256) void k_agg2(const int* __restrict__ rowptr, const int* __restrict__ csr,
                                              const float* __restrict__ h2l, const float* __restrict__ h2r,
                                              const float* __restrict__ b2, float* __restrict__ out) {
    int wave = (blockIdx.x * 256 + threadIdx.x) >> 6;
    int lane = threadIdx.x & 63;
    if (wave >= N_NODES) return;
    int start = rowptr[wave];
    int end = rowptr[wave + 1];
    bool act = lane < OUT_C;
    int cl = act ? lane : 0;
    float acc = 0.0f;
    int e = start;
    for (; e + 4 <= end; e += 4) {
        int s0 = csr[e], s1 = csr[e + 1], s2 = csr[e + 2], s3 = csr[e + 3];
        float v0 = h2l[(size_t)s0 * OUT_C + cl];
        float v1 = h2l[(size_t)s1 * OUT_C + cl];
        float v2 = h2l[(size_t)s2 * OUT_C + cl];
        float v3 = h2l[(size_t)s3 * OUT_C + cl];
        acc += (v0 + v1) + (v2 + v3);
    }
    for (; e < end; ++e)
        acc += h2l[(size_t)csr[e] * OUT_C + cl];
    float deg = (float)(end - start);
    float mean = acc / fmaxf(deg, 1.0f);
    float v = -1e30f;
    if (act)
        v = mean + h2r[(size_t)wave * OUT_C + lane] + b2[lane];
    float m = v;
#pragma unroll
    for (int off = 32; off > 0; off >>= 1)
        m = fmaxf(m, __shfl_xor(m, off));
    float ex = act ? expf(v - m) : 0.0f;
    float s = ex;
#pragma unroll
    for (int off = 32; off > 0; off >>= 1)
        s += __shfl_xor(s, off);
    float res = v - m - logf(s);
    if (act)
        out[(size_t)wave * OUT_C + lane] = res;
}

// ----------------------------------------------------------------
extern "C" void kernel_launch(void* const* d_in, const int* in_sizes, int n_in,
                              void* d_out, int out_size, void* d_ws, size_t ws_size,
                              hipStream_t stream) {
    const float* x   = (const float*)d_in[0];
    const int*   ei  = (const int*)d_in[1];
    const float* Wl1 = (const float*)d_in[2];
    const float* b1  = (const float*)d_in[3];
    const float* Wr1 = (const float*)d_in[4];
    const float* Wl2 = (const float*)d_in[5];
    const float* b2  = (const float*)d_in[6];
    const float* Wr2 = (const float*)d_in[7];

    // ws layout (4B units): hist[N] | cursor[N] | rowptr[N+1] | bsum[512] | boff[512] |
    //                       csr[E] | h1l[N*64] | h1r[N*64] | h2l[N*40] | h2r[N*40]
    size_t u = 0;
    int*   hist   = (int*)d_ws;                 u += N_NODES;
    int*   cursor = (int*)d_ws + u;             u += N_NODES;
    int*   rowptr = (int*)d_ws + u;             u += N_NODES + 1;
    int*   bsum   = (int*)d_ws + u;             u += 512;
    int*   boff   = (int*)d_ws + u;             u += 512;
    int*   csr    = (int*)d_ws + u;             u += E_EDGES;
    float* h1l    = (float*)d_ws + u;           u += (size_t)N_NODES * HID_C;
    float* h1r    = (float*)d_ws + u;           u += (size_t)N_NODES * HID_C;
    float* h2l    = (float*)d_ws + u;           u += (size_t)N_NODES * OUT_C;
    float* h2r    = (float*)d_ws + u;           u += (size_t)N_NODES * OUT_C;
    if (ws_size < u * 4) return;

    hipMemsetAsync(hist, 0, N_NODES * sizeof(int), stream);
    hipMemsetAsync(cursor, 0, N_NODES * sizeof(int), stream);

    const int* src = ei;
    const int* dst = ei + E_EDGES;

    k_hist<<<(E_EDGES + 255) / 256, 256, 0, stream>>>(dst, hist);
    k_scanA<<<NB, 256, 0, stream>>>(hist, bsum);
    k_scanB<<<1, 512, 0, stream>>>(bsum, boff, rowptr);
    k_scanC<<<NB, 256, 0, stream>>>(hist, boff, rowptr);
    k_fill<<<(E_EDGES + 255) / 256, 256, 0, stream>>>(ei, rowptr, cursor, csr);

    k_gemm1<<<(N_NODES + 63) / 64, 256, 0, stream>>>(x, Wl1, Wr1, h1l, h1r);
    k_agg1<<<N_NODES / 4, 256, 0, stream>>>(rowptr, csr, h1l, h1r, b1);
    k_gemm2<<<(N_NODES + 127) / 128, 320, 0, stream>>>(h1r, Wl2, Wr2, h2l, h2r);
    k_agg2<<<N_NODES / 4, 256, 0, stream>>>(rowptr, csr, h2l, h2r, b2, (float*)d_out);
}

// Round 4
// 483.237 us; speedup vs baseline: 1.9115x; 1.0554x over previous
//
#include <hip/hip_runtime.h>
#include <hip/hip_bf16.h>

#define N_NODES 100000
#define E_EDGES 1600000
#define IN_C 128
#define HID_C 64
#define OUT_C 40
#define NB 391        // ceil(N_NODES/256)
#define NGRP 8        // XCD count
#define RANGE (N_NODES / NGRP)   // 12500 exact

typedef unsigned short ushort_t;
typedef unsigned int uint_t;

__device__ __forceinline__ float bfu2f(ushort_t u) {
    return __uint_as_float(((uint_t)u) << 16);
}
__device__ __forceinline__ ushort_t f2bfu(float f) {   // RNE
    uint_t u = __float_as_uint(f);
    return (ushort_t)((u + 0x7FFFu + ((u >> 16) & 1u)) >> 16);
}

// ---------------------------------------------------------------- in-degree histogram (int)
__global__ void k_hist(const int* __restrict__ dst, int* __restrict__ hist) {
    int i = blockIdx.x * 256 + threadIdx.x;
    if (i < E_EDGES) atomicAdd(&hist[dst[i]], 1);
}

// ---------------------------------------------------------------- scan A: per-block sums
__global__ __launch_bounds__(256) void k_scanA(const int* __restrict__ hist, int* __restrict__ bsum) {
    __shared__ int tmp[256];
    int i = blockIdx.x * 256 + threadIdx.x;
    int v = (i < N_NODES) ? hist[i] : 0;
    tmp[threadIdx.x] = v;
    __syncthreads();
    for (int off = 128; off > 0; off >>= 1) {
        if (threadIdx.x < off) tmp[threadIdx.x] += tmp[threadIdx.x + off];
        __syncthreads();
    }
    if (threadIdx.x == 0) bsum[blockIdx.x] = tmp[0];
}

// ---------------------------------------------------------------- scan B: exclusive scan of block sums (1 block)
__global__ __launch_bounds__(512) void k_scanB(const int* __restrict__ bsum, int* __restrict__ boff,
                                               int* __restrict__ rowptr) {
    __shared__ int tmp[512];
    int t = threadIdx.x;
    int v = (t < NB) ? bsum[t] : 0;
    tmp[t] = v;
    __syncthreads();
    for (int off = 1; off < 512; off <<= 1) {
        int a = (t >= off) ? tmp[t - off] : 0;
        __syncthreads();
        tmp[t] += a;
        __syncthreads();
    }
    if (t < NB) boff[t] = tmp[t] - v;   // exclusive
    if (t == 0) rowptr[N_NODES] = E_EDGES;
}

// ---------------------------------------------------------------- scan C: rowptr[i] = boff[b] + exclusive-in-block
__global__ __launch_bounds__(256) void k_scanC(const int* __restrict__ hist, const int* __restrict__ boff,
                                               int* __restrict__ rowptr) {
    __shared__ int tmp[256];
    int i = blockIdx.x * 256 + threadIdx.x;
    int t = threadIdx.x;
    int v = (i < N_NODES) ? hist[i] : 0;
    tmp[t] = v;
    __syncthreads();
    for (int off = 1; off < 256; off <<= 1) {
        int a = (t >= off) ? tmp[t - off] : 0;
        __syncthreads();
        tmp[t] += a;
        __syncthreads();
    }
    if (i < N_NODES) rowptr[i] = boff[blockIdx.x] + tmp[t] - v;
}

// ---------------------------------------------------------------- fill CSR, XCD-range-partitioned:
// group g (= blockIdx&7, round-robin -> same XCD) scans all edges, writes only its dst range.
// Each 64B csr line is dirtied by exactly one XCD -> full-line writeback once.
__global__ __launch_bounds__(256) void k_fill2(const int* __restrict__ src, const int* __restrict__ dst,
                                               const int* __restrict__ rowptr,
                                               int* __restrict__ cursor, int* __restrict__ csr) {
    int g = blockIdx.x & (NGRP - 1);
    int lo = g * RANGE, hi = lo + RANGE;
    int nchunk = gridDim.x >> 3;
    int stride = nchunk * 256;
    for (int i = (blockIdx.x >> 3) * 256 + threadIdx.x; i < E_EDGES; i += stride) {
        int d = dst[i];
        if (d >= lo && d < hi) {
            int s = src[i];
            int pos = atomicAdd(&cursor[d], 1);
            csr[rowptr[d] + pos] = s;
        }
    }
}

// ---------------------------------------------------------------- GEMM1: h1l(bf16) = x@Wl1, h1r(f32) = x@Wr1
__global__ __launch_bounds__(256) void k_gemm1(const float* __restrict__ x,
                                               const float* __restrict__ Wl,
                                               const float* __restrict__ Wr,
                                               ushort_t* __restrict__ h1l,
                                               float* __restrict__ h1r) {
    __shared__ float xs[64 * 132];
    const int t = threadIdx.x;
    const int row_base = blockIdx.x * 64;

    for (int i = t; i < 64 * 32; i += 256) {
        int row = i >> 5, seg = i & 31;
        int gr = row_base + row;
        float4 val = make_float4(0.f, 0.f, 0.f, 0.f);
        if (gr < N_NODES)
            val = *(const float4*)(x + (size_t)gr * IN_C + seg * 4);
        *(float4*)(xs + row * 132 + seg * 4) = val;
    }
    __syncthreads();

    const int c0 = (t & 15) * 4;
    const int r0 = (t >> 4) * 4;
    float accl[4][4] = {};
    float accr[4][4] = {};

#pragma unroll 4
    for (int k = 0; k < IN_C; ++k) {
        float4 wl4 = *(const float4*)(Wl + k * HID_C + c0);
        float4 wr4 = *(const float4*)(Wr + k * HID_C + c0);
        float wl[4] = {wl4.x, wl4.y, wl4.z, wl4.w};
        float wr[4] = {wr4.x, wr4.y, wr4.z, wr4.w};
        float xv[4];
#pragma unroll
        for (int r = 0; r < 4; ++r) xv[r] = xs[(r0 + r) * 132 + k];
#pragma unroll
        for (int r = 0; r < 4; ++r) {
#pragma unroll
            for (int j = 0; j < 4; ++j) {
                accl[r][j] = fmaf(xv[r], wl[j], accl[r][j]);
                accr[r][j] = fmaf(xv[r], wr[j], accr[r][j]);
            }
        }
    }

#pragma unroll
    for (int r = 0; r < 4; ++r) {
        int gr = row_base + r0 + r;
        if (gr < N_NODES) {
            ushort4 uv;
            uv.x = f2bfu(accl[r][0]); uv.y = f2bfu(accl[r][1]);
            uv.z = f2bfu(accl[r][2]); uv.w = f2bfu(accl[r][3]);
            *(ushort4*)(h1l + (size_t)gr * HID_C + c0) = uv;
            *(float4*)(h1r + (size_t)gr * HID_C + c0) =
                make_float4(accr[r][0], accr[r][1], accr[r][2], accr[r][3]);
        }
    }
}

// ---------------------------------------------------------------- agg1 (bf16 gather) fused relu(mean + root + b1) -> h1r in place
__global__ __launch_bounds__(256) void k_agg1(const int* __restrict__ rowptr, const int* __restrict__ csr,
                                              const ushort_t* __restrict__ h1l, float* __restrict__ h1r,
                                              const float* __restrict__ b1) {
    int wave = (blockIdx.x * 256 + threadIdx.x) >> 6;
    int lane = threadIdx.x & 63;
    if (wave >= N_NODES) return;
    int start = rowptr[wave];
    int end = rowptr[wave + 1];
    float acc = 0.0f;
    int e = start;
    for (; e + 4 <= end; e += 4) {
        int s0 = csr[e], s1 = csr[e + 1], s2 = csr[e + 2], s3 = csr[e + 3];
        float v0 = bfu2f(h1l[(size_t)s0 * HID_C + lane]);
        float v1 = bfu2f(h1l[(size_t)s1 * HID_C + lane]);
        float v2 = bfu2f(h1l[(size_t)s2 * HID_C + lane]);
        float v3 = bfu2f(h1l[(size_t)s3 * HID_C + lane]);
        acc += (v0 + v1) + (v2 + v3);
    }
    for (; e < end; ++e)
        acc += bfu2f(h1l[(size_t)csr[e] * HID_C + lane]);
    float deg = (float)(end - start);
    float mean = acc / fmaxf(deg, 1.0f);
    size_t idx = (size_t)wave * HID_C + lane;
    float v = mean + h1r[idx] + b1[lane];
    h1r[idx] = fmaxf(v, 0.0f);
}

// ---------------------------------------------------------------- GEMM2: h2l(bf16) = hid@Wl2, h2r(f32) = hid@Wr2
__global__ __launch_bounds__(320) void k_gemm2(const float* __restrict__ hid,
                                               const float* __restrict__ Wl,
                                               const float* __restrict__ Wr,
                                               ushort_t* __restrict__ h2l,
                                               float* __restrict__ h2r) {
    __shared__ float hs[128 * 65];
    __shared__ float2 Wp[HID_C * OUT_C];
    const int t = threadIdx.x;

    for (int i = t; i < HID_C * OUT_C; i += 320)
        Wp[i] = make_float2(Wl[i], Wr[i]);

    const int row_base = blockIdx.x * 128;
    for (int i = t; i < 128 * 64; i += 320) {
        int row = i >> 6, c = i & 63;
        int gr = row_base + row;
        hs[row * 65 + c] = (gr < N_NODES) ? hid[(size_t)gr * HID_C + c] : 0.0f;
    }
    __syncthreads();

    const int c0 = (t % 10) * 4;
    const int r0 = (t / 10) * 4;
    float accl[4][4] = {};
    float accr[4][4] = {};

#pragma unroll 4
    for (int k = 0; k < HID_C; ++k) {
        float4 wa = *(const float4*)&Wp[k * OUT_C + c0];
        float4 wb = *(const float4*)&Wp[k * OUT_C + c0 + 2];
        float wl[4] = {wa.x, wa.z, wb.x, wb.z};
        float wr[4] = {wa.y, wa.w, wb.y, wb.w};
#pragma unroll
        for (int r = 0; r < 4; ++r) {
            float xv = hs[(r0 + r) * 65 + k];
#pragma unroll
            for (int j = 0; j < 4; ++j) {
                accl[r][j] = fmaf(xv, wl[j], accl[r][j]);
                accr[r][j] = fmaf(xv, wr[j], accr[r][j]);
            }
        }
    }

#pragma unroll
    for (int r = 0; r < 4; ++r) {
        int gr = row_base + r0 + r;
        if (gr < N_NODES) {
            ushort4 uv;
            uv.x = f2bfu(accl[r][0]); uv.y = f2bfu(accl[r][1]);
            uv.z = f2bfu(accl[r][2]); uv.w = f2bfu(accl[r][3]);
            *(ushort4*)(h2l + (size_t)gr * OUT_C + c0) = uv;
            *(float4*)(h2r + (size_t)gr * OUT_C + c0) =
                make_float4(accr[r][0], accr[r][1], accr[r][2], accr[r][3]);
        }
    }
}

// ---------------------------------------------------------------- agg2 (bf16 gather) fused log_softmax(mean + root + b2)
__global__ __launch_bounds__(256) void k_agg2(const int* __restrict__ rowptr, const int* __restrict__ csr,
                                              const ushort_t* __restrict__ h2l, const float* __restrict__ h2r,
                                              const float* __restrict__ b2, float* __restrict__ out) {
    int wave = (blockIdx.x * 256 + threadIdx.x) >> 6;
    int lane = threadIdx.x & 63;
    if (wave >= N_NODES) return;
    int start = rowptr[wave];
    int end = rowptr[wave + 1];
    bool act = lane < OUT_C;
    int cl = act ? lane : 0;
    float acc = 0.0f;
    int e = start;
    for (; e + 4 <= end; e += 4) {
        int s0 = csr[e], s1 = csr[e + 1], s2 = csr[e + 2], s3 = csr[e + 3];
        float v0 = bfu2f(h2l[(size_t)s0 * OUT_C + cl]);
        float v1 = bfu2f(h2l[(size_t)s1 * OUT_C + cl]);
        float v2 = bfu2f(h2l[(size_t)s2 * OUT_C + cl]);
        float v3 = bfu2f(h2l[(size_t)s3 * OUT_C + cl]);
        acc += (v0 + v1) + (v2 + v3);
    }
    for (; e < end; ++e)
        acc += bfu2f(h2l[(size_t)csr[e] * OUT_C + cl]);
    float deg = (float)(end - start);
    float mean = acc / fmaxf(deg, 1.0f);
    float v = -1e30f;
    if (act)
        v = mean + h2r[(size_t)wave * OUT_C + lane] + b2[lane];
    float m = v;
#pragma unroll
    for (int off = 32; off > 0; off >>= 1)
        m = fmaxf(m, __shfl_xor(m, off));
    float ex = act ? expf(v - m) : 0.0f;
    float s = ex;
#pragma unroll
    for (int off = 32; off > 0; off >>= 1)
        s += __shfl_xor(s, off);
    float res = v - m - logf(s);
    if (act)
        out[(size_t)wave * OUT_C + lane] = res;
}

// ----------------------------------------------------------------
extern "C" void kernel_launch(void* const* d_in, const int* in_sizes, int n_in,
                              void* d_out, int out_size, void* d_ws, size_t ws_size,
                              hipStream_t stream) {
    const float* x   = (const float*)d_in[0];
    const int*   ei  = (const int*)d_in[1];
    const float* Wl1 = (const float*)d_in[2];
    const float* b1  = (const float*)d_in[3];
    const float* Wr1 = (const float*)d_in[4];
    const float* Wl2 = (const float*)d_in[5];
    const float* b2  = (const float*)d_in[6];
    const float* Wr2 = (const float*)d_in[7];

    // ws layout (4B units): hist[N] | cursor[N] | rowptr[N+1] | bsum[512] | boff[512] |
    //   csr[E] | h1l bf16[N*64] | h1r f32[N*64] | h2l bf16[N*40] | h2r f32[N*40]
    size_t u = 0;
    int*      hist   = (int*)d_ws;             u += N_NODES;
    int*      cursor = (int*)d_ws + u;         u += N_NODES;
    int*      rowptr = (int*)d_ws + u;         u += N_NODES + 1;
    int*      bsum   = (int*)d_ws + u;         u += 512;
    int*      boff   = (int*)d_ws + u;         u += 512;
    int*      csr    = (int*)d_ws + u;         u += E_EDGES;
    ushort_t* h1l    = (ushort_t*)((int*)d_ws + u); u += (size_t)N_NODES * HID_C / 2;
    float*    h1r    = (float*)d_ws + u;       u += (size_t)N_NODES * HID_C;
    ushort_t* h2l    = (ushort_t*)((int*)d_ws + u); u += (size_t)N_NODES * OUT_C / 2;
    float*    h2r    = (float*)d_ws + u;       u += (size_t)N_NODES * OUT_C;
    if (ws_size < u * 4) return;

    hipMemsetAsync(hist, 0, N_NODES * sizeof(int), stream);
    hipMemsetAsync(cursor, 0, N_NODES * sizeof(int), stream);

    const int* src = ei;
    const int* dst = ei + E_EDGES;

    k_hist<<<(E_EDGES + 255) / 256, 256, 0, stream>>>(dst, hist);
    k_scanA<<<NB, 256, 0, stream>>>(hist, bsum);
    k_scanB<<<1, 512, 0, stream>>>(bsum, boff, rowptr);
    k_scanC<<<NB, 256, 0, stream>>>(hist, boff, rowptr);
    k_fill2<<<NGRP * 640, 256, 0, stream>>>(src, dst, rowptr, cursor, csr);

    k_gemm1<<<(N_NODES + 63) / 64, 256, 0, stream>>>(x, Wl1, Wr1, h1l, h1r);
    k_agg1<<<N_NODES / 4, 256, 0, stream>>>(rowptr, csr, h1l, h1r, b1);
    k_gemm2<<<(N_NODES + 127) / 128, 320, 0, stream>>>(h1r, Wl2, Wr2, h2l, h2r);
    k_agg2<<<N_NODES / 4, 256, 0, stream>>>(rowptr, csr, h2l, h2r, b2, (float*)d_out);
}

// Round 5
// 421.283 us; speedup vs baseline: 2.1926x; 1.1471x over previous
//
#include <hip/hip_runtime.h>
#include <hip/hip_bf16.h>

#define N_NODES 100000
#define E_EDGES 1600000
#define IN_C 128
#define HID_C 64
#define OUT_C 40
#define NB 391        // ceil(N_NODES/256)
#define NGRP 8        // XCD count
#define RANGE (N_NODES / NGRP)   // 12500 exact

typedef unsigned short ushort_t;
typedef unsigned int uint_t;
typedef __attribute__((ext_vector_type(8))) short bf16x8;
typedef __attribute__((ext_vector_type(4))) float f32x4;

__device__ __forceinline__ float bfu2f(ushort_t u) {
    return __uint_as_float(((uint_t)u) << 16);
}
__device__ __forceinline__ ushort_t f2bfu(float f) {   // RNE
    uint_t u = __float_as_uint(f);
    return (ushort_t)((u + 0x7FFFu + ((u >> 16) & 1u)) >> 16);
}

// ---------------------------------------------------------------- in-degree histogram (int)
__global__ void k_hist(const int* __restrict__ dst, int* __restrict__ hist) {
    int i = blockIdx.x * 256 + threadIdx.x;
    if (i < E_EDGES) atomicAdd(&hist[dst[i]], 1);
}

// ---------------------------------------------------------------- scan A: per-block sums
__global__ __launch_bounds__(256) void k_scanA(const int* __restrict__ hist, int* __restrict__ bsum) {
    __shared__ int tmp[256];
    int i = blockIdx.x * 256 + threadIdx.x;
    int v = (i < N_NODES) ? hist[i] : 0;
    tmp[threadIdx.x] = v;
    __syncthreads();
    for (int off = 128; off > 0; off >>= 1) {
        if (threadIdx.x < off) tmp[threadIdx.x] += tmp[threadIdx.x + off];
        __syncthreads();
    }
    if (threadIdx.x == 0) bsum[blockIdx.x] = tmp[0];
}

// ---------------------------------------------------------------- scan B: exclusive scan of block sums (1 block)
__global__ __launch_bounds__(512) void k_scanB(const int* __restrict__ bsum, int* __restrict__ boff,
                                               int* __restrict__ rowptr) {
    __shared__ int tmp[512];
    int t = threadIdx.x;
    int v = (t < NB) ? bsum[t] : 0;
    tmp[t] = v;
    __syncthreads();
    for (int off = 1; off < 512; off <<= 1) {
        int a = (t >= off) ? tmp[t - off] : 0;
        __syncthreads();
        tmp[t] += a;
        __syncthreads();
    }
    if (t < NB) boff[t] = tmp[t] - v;   // exclusive
    if (t == 0) rowptr[N_NODES] = E_EDGES;
}

// ---------------------------------------------------------------- scan C: rowptr[i] = boff[b] + exclusive-in-block
__global__ __launch_bounds__(256) void k_scanC(const int* __restrict__ hist, const int* __restrict__ boff,
                                               int* __restrict__ rowptr) {
    __shared__ int tmp[256];
    int i = blockIdx.x * 256 + threadIdx.x;
    int t = threadIdx.x;
    int v = (i < N_NODES) ? hist[i] : 0;
    tmp[t] = v;
    __syncthreads();
    for (int off = 1; off < 256; off <<= 1) {
        int a = (t >= off) ? tmp[t - off] : 0;
        __syncthreads();
        tmp[t] += a;
        __syncthreads();
    }
    if (i < N_NODES) rowptr[i] = boff[blockIdx.x] + tmp[t] - v;
}

// ---------------------------------------------------------------- fill CSR, XCD-range-partitioned
__global__ __launch_bounds__(256) void k_fill2(const int* __restrict__ src, const int* __restrict__ dst,
                                               const int* __restrict__ rowptr,
                                               int* __restrict__ cursor, int* __restrict__ csr) {
    int g = blockIdx.x & (NGRP - 1);
    int lo = g * RANGE, hi = lo + RANGE;
    int nchunk = gridDim.x >> 3;
    int stride = nchunk * 256;
    for (int i = (blockIdx.x >> 3) * 256 + threadIdx.x; i < E_EDGES; i += stride) {
        int d = dst[i];
        if (d >= lo && d < hi) {
            int s = src[i];
            int pos = atomicAdd(&cursor[d], 1);
            csr[rowptr[d] + pos] = s;
        }
    }
}

// ---------------------------------------------------------------- weight prep: bf16, transposed, l|r concatenated
// Wt1: [n=128][k=128]  (n<64: Wl1, else Wr1);  Wt2: [n=80][k=64] (n<40: Wl2, else Wr2)
__global__ __launch_bounds__(256) void k_wprep(const float* __restrict__ Wl1, const float* __restrict__ Wr1,
                                               const float* __restrict__ Wl2, const float* __restrict__ Wr2,
                                               ushort_t* __restrict__ Wt1, ushort_t* __restrict__ Wt2) {
    int i = blockIdx.x * 256 + threadIdx.x;
    if (i < 128 * 128) {
        int n = i >> 7, k = i & 127;
        float v = (n < 64) ? Wl1[k * 64 + n] : Wr1[k * 64 + (n - 64)];
        Wt1[n * 128 + k] = f2bfu(v);
    }
    if (i < 80 * 64) {
        int n = i >> 6, k = i & 63;
        float v = (n < 40) ? Wl2[k * 40 + n] : Wr2[k * 40 + (n - 40)];
        Wt2[n * 64 + k] = f2bfu(v);
    }
}

// ---------------------------------------------------------------- GEMM1 (MFMA): [h1l|h1r] = x @ [Wl1|Wr1]
// block = 4 waves, 64 rows; wave = 16 rows x 128 cols; K=128 in 4 steps of 32
__global__ __launch_bounds__(256) void k_gemm1(const float* __restrict__ x,
                                               const ushort_t* __restrict__ Wt,  // [128][128] bf16
                                               ushort_t* __restrict__ h1l,
                                               float* __restrict__ h1r) {
    __shared__ ushort_t xs[64 * 136];    // rows x K, pad stride 136
    __shared__ ushort_t wsm[128 * 136];  // n x K, pad stride 136
    const int t = threadIdx.x;
    const int row_base = blockIdx.x * 64;

    for (int i = t; i < 128 * 16; i += 256) {        // W: 128 n x 16 segs of 8 bf16
        int n = i >> 4, seg = i & 15;
        uint4 v = *(const uint4*)(Wt + n * 128 + seg * 8);
        *(uint4*)(wsm + n * 136 + seg * 8) = v;
    }
    for (int i = t; i < 64 * 32; i += 256) {         // x: 64 rows x 32 float4 -> bf16
        int row = i >> 5, seg = i & 31;
        int gr = row_base + row;
        float4 v = make_float4(0.f, 0.f, 0.f, 0.f);
        if (gr < N_NODES) v = *(const float4*)(x + (size_t)gr * IN_C + seg * 4);
        ushort4 u;
        u.x = f2bfu(v.x); u.y = f2bfu(v.y); u.z = f2bfu(v.z); u.w = f2bfu(v.w);
        *(ushort4*)(xs + row * 136 + seg * 4) = u;
    }
    __syncthreads();

    const int wv = t >> 6, lane = t & 63;
    const int m = lane & 15, quad = lane >> 4;
    const int m0 = wv * 16;

    bf16x8 a[4];
#pragma unroll
    for (int kk = 0; kk < 4; ++kk)
        a[kk] = *(const bf16x8*)(xs + (m0 + m) * 136 + kk * 32 + quad * 8);

    f32x4 acc[8];
#pragma unroll
    for (int nt = 0; nt < 8; ++nt) acc[nt] = (f32x4){0.f, 0.f, 0.f, 0.f};

#pragma unroll
    for (int nt = 0; nt < 8; ++nt) {
#pragma unroll
        for (int kk = 0; kk < 4; ++kk) {
            bf16x8 b = *(const bf16x8*)(wsm + (nt * 16 + m) * 136 + kk * 32 + quad * 8);
            acc[nt] = __builtin_amdgcn_mfma_f32_16x16x32_bf16(a[kk], b, acc[nt], 0, 0, 0);
        }
    }

    const int grow_base = row_base + m0 + quad * 4;
#pragma unroll
    for (int r = 0; r < 4; ++r) {
        int grow = grow_base + r;
        if (grow < N_NODES) {
#pragma unroll
            for (int nt = 0; nt < 4; ++nt)
                h1l[(size_t)grow * HID_C + nt * 16 + m] = f2bfu(acc[nt][r]);
#pragma unroll
            for (int nt = 4; nt < 8; ++nt)
                h1r[(size_t)grow * HID_C + (nt - 4) * 16 + m] = acc[nt][r];
        }
    }
}

// ---------------------------------------------------------------- agg1 (bf16 gather) fused relu(mean + root + b1) -> h1r
__global__ __launch_bounds__(256) void k_agg1(const int* __restrict__ rowptr, const int* __restrict__ csr,
                                              const ushort_t* __restrict__ h1l, float* __restrict__ h1r,
                                              const float* __restrict__ b1) {
    int wave = (blockIdx.x * 256 + threadIdx.x) >> 6;
    int lane = threadIdx.x & 63;
    if (wave >= N_NODES) return;
    int start = rowptr[wave];
    int end = rowptr[wave + 1];
    float acc = 0.0f;
    int e = start;
    for (; e + 8 <= end; e += 8) {
        int s0 = csr[e], s1 = csr[e + 1], s2 = csr[e + 2], s3 = csr[e + 3];
        int s4 = csr[e + 4], s5 = csr[e + 5], s6 = csr[e + 6], s7 = csr[e + 7];
        float v0 = bfu2f(h1l[(size_t)s0 * HID_C + lane]);
        float v1 = bfu2f(h1l[(size_t)s1 * HID_C + lane]);
        float v2 = bfu2f(h1l[(size_t)s2 * HID_C + lane]);
        float v3 = bfu2f(h1l[(size_t)s3 * HID_C + lane]);
        float v4 = bfu2f(h1l[(size_t)s4 * HID_C + lane]);
        float v5 = bfu2f(h1l[(size_t)s5 * HID_C + lane]);
        float v6 = bfu2f(h1l[(size_t)s6 * HID_C + lane]);
        float v7 = bfu2f(h1l[(size_t)s7 * HID_C + lane]);
        acc += ((v0 + v1) + (v2 + v3)) + ((v4 + v5) + (v6 + v7));
    }
    for (; e < end; ++e)
        acc += bfu2f(h1l[(size_t)csr[e] * HID_C + lane]);
    float deg = (float)(end - start);
    float mean = acc / fmaxf(deg, 1.0f);
    size_t idx = (size_t)wave * HID_C + lane;
    float v = mean + h1r[idx] + b1[lane];
    h1r[idx] = fmaxf(v, 0.0f);
}

// ---------------------------------------------------------------- GEMM2 (MFMA): [h2l|h2r] = hid @ [Wl2|Wr2]
// block = 4 waves, 64 rows; wave = 16 rows x 80 cols; K=64 in 2 steps of 32
__global__ __launch_bounds__(256) void k_gemm2(const float* __restrict__ hid,
                                               const ushort_t* __restrict__ Wt,  // [80][64] bf16
                                               ushort_t* __restrict__ h2l,
                                               float* __restrict__ h2r) {
    __shared__ ushort_t hs[64 * 72];
    __shared__ ushort_t wsm[80 * 72];
    const int t = threadIdx.x;
    const int row_base = blockIdx.x * 64;

    for (int i = t; i < 80 * 8; i += 256) {          // W: 80 n x 8 segs of 8
        int n = i >> 3, seg = i & 7;
        uint4 v = *(const uint4*)(Wt + n * 64 + seg * 8);
        *(uint4*)(wsm + n * 72 + seg * 8) = v;
    }
    for (int i = t; i < 64 * 16; i += 256) {         // hid: 64 rows x 16 float4 -> bf16
        int row = i >> 4, seg = i & 15;
        int gr = row_base + row;
        float4 v = make_float4(0.f, 0.f, 0.f, 0.f);
        if (gr < N_NODES) v = *(const float4*)(hid + (size_t)gr * HID_C + seg * 4);
        ushort4 u;
        u.x = f2bfu(v.x); u.y = f2bfu(v.y); u.z = f2bfu(v.z); u.w = f2bfu(v.w);
        *(ushort4*)(hs + row * 72 + seg * 4) = u;
    }
    __syncthreads();

    const int wv = t >> 6, lane = t & 63;
    const int m = lane & 15, quad = lane >> 4;
    const int m0 = wv * 16;

    bf16x8 a[2];
#pragma unroll
    for (int kk = 0; kk < 2; ++kk)
        a[kk] = *(const bf16x8*)(hs + (m0 + m) * 72 + kk * 32 + quad * 8);

    f32x4 acc[5];
#pragma unroll
    for (int nt = 0; nt < 5; ++nt) acc[nt] = (f32x4){0.f, 0.f, 0.f, 0.f};

#pragma unroll
    for (int nt = 0; nt < 5; ++nt) {
#pragma unroll
        for (int kk = 0; kk < 2; ++kk) {
            bf16x8 b = *(const bf16x8*)(wsm + (nt * 16 + m) * 72 + kk * 32 + quad * 8);
            acc[nt] = __builtin_amdgcn_mfma_f32_16x16x32_bf16(a[kk], b, acc[nt], 0, 0, 0);
        }
    }

    const int grow_base = row_base + m0 + quad * 4;
#pragma unroll
    for (int r = 0; r < 4; ++r) {
        int grow = grow_base + r;
        if (grow < N_NODES) {
#pragma unroll
            for (int nt = 0; nt < 5; ++nt) {
                int col = nt * 16 + m;
                float v = acc[nt][r];
                if (col < OUT_C) h2l[(size_t)grow * OUT_C + col] = f2bfu(v);
                else             h2r[(size_t)grow * OUT_C + (col - OUT_C)] = v;
            }
        }
    }
}

// ---------------------------------------------------------------- agg2 (bf16 gather) fused log_softmax(mean + root + b2)
__global__ __launch_bounds__(256) void k_agg2(const int* __restrict__ rowptr, const int* __restrict__ csr,
                                              const ushort_t* __restrict__ h2l, const float* __restrict__ h2r,
                                              const float* __restrict__ b2, float* __restrict__ out) {
    int wave = (blockIdx.x * 256 + threadIdx.x) >> 6;
    int lane = threadIdx.x & 63;
    if (wave >= N_NODES) return;
    int start = rowptr[wave];
    int end = rowptr[wave + 1];
    bool act = lane < OUT_C;
    int cl = act ? lane : 0;
    float acc = 0.0f;
    int e = start;
    for (; e + 8 <= end; e += 8) {
        int s0 = csr[e], s1 = csr[e + 1], s2 = csr[e + 2], s3 = csr[e + 3];
        int s4 = csr[e + 4], s5 = csr[e + 5], s6 = csr[e + 6], s7 = csr[e + 7];
        float v0 = bfu2f(h2l[(size_t)s0 * OUT_C + cl]);
        float v1 = bfu2f(h2l[(size_t)s1 * OUT_C + cl]);
        float v2 = bfu2f(h2l[(size_t)s2 * OUT_C + cl]);
        float v3 = bfu2f(h2l[(size_t)s3 * OUT_C + cl]);
        float v4 = bfu2f(h2l[(size_t)s4 * OUT_C + cl]);
        float v5 = bfu2f(h2l[(size_t)s5 * OUT_C + cl]);
        float v6 = bfu2f(h2l[(size_t)s6 * OUT_C + cl]);
        float v7 = bfu2f(h2l[(size_t)s7 * OUT_C + cl]);
        acc += ((v0 + v1) + (v2 + v3)) + ((v4 + v5) + (v6 + v7));
    }
    for (; e < end; ++e)
        acc += bfu2f(h2l[(size_t)csr[e] * OUT_C + cl]);
    float deg = (float)(end - start);
    float mean = acc / fmaxf(deg, 1.0f);
    float v = -1e30f;
    if (act)
        v = mean + h2r[(size_t)wave * OUT_C + lane] + b2[lane];
    float m = v;
#pragma unroll
    for (int off = 32; off > 0; off >>= 1)
        m = fmaxf(m, __shfl_xor(m, off));
    float ex = act ? expf(v - m) : 0.0f;
    float s = ex;
#pragma unroll
    for (int off = 32; off > 0; off >>= 1)
        s += __shfl_xor(s, off);
    float res = v - m - logf(s);
    if (act)
        out[(size_t)wave * OUT_C + lane] = res;
}

// ----------------------------------------------------------------
extern "C" void kernel_launch(void* const* d_in, const int* in_sizes, int n_in,
                              void* d_out, int out_size, void* d_ws, size_t ws_size,
                              hipStream_t stream) {
    const float* x   = (const float*)d_in[0];
    const int*   ei  = (const int*)d_in[1];
    const float* Wl1 = (const float*)d_in[2];
    const float* b1  = (const float*)d_in[3];
    const float* Wr1 = (const float*)d_in[4];
    const float* Wl2 = (const float*)d_in[5];
    const float* b2  = (const float*)d_in[6];
    const float* Wr2 = (const float*)d_in[7];

    // ws layout (4B units): hist | cursor | rowptr | bsum | boff | csr | [align16] |
    //   Wt1 bf16[128*128] | Wt2 bf16[80*64] | h1l bf16[N*64] | h1r f32[N*64] | h2l bf16[N*40] | h2r f32[N*40]
    size_t u = 0;
    int*      hist   = (int*)d_ws;             u += N_NODES;
    int*      cursor = (int*)d_ws + u;         u += N_NODES;
    int*      rowptr = (int*)d_ws + u;         u += N_NODES + 1;
    int*      bsum   = (int*)d_ws + u;         u += 512;
    int*      boff   = (int*)d_ws + u;         u += 512;
    int*      csr    = (int*)d_ws + u;         u += E_EDGES;
    u = (u + 3) & ~(size_t)3;                  // 16B align
    ushort_t* Wt1    = (ushort_t*)((int*)d_ws + u); u += 128 * 128 / 2;
    ushort_t* Wt2    = (ushort_t*)((int*)d_ws + u); u += 80 * 64 / 2;
    ushort_t* h1l    = (ushort_t*)((int*)d_ws + u); u += (size_t)N_NODES * HID_C / 2;
    float*    h1r    = (float*)d_ws + u;       u += (size_t)N_NODES * HID_C;
    ushort_t* h2l    = (ushort_t*)((int*)d_ws + u); u += (size_t)N_NODES * OUT_C / 2;
    float*    h2r    = (float*)d_ws + u;       u += (size_t)N_NODES * OUT_C;
    if (ws_size < u * 4) return;

    hipMemsetAsync(hist, 0, N_NODES * sizeof(int), stream);
    hipMemsetAsync(cursor, 0, N_NODES * sizeof(int), stream);

    const int* src = ei;
    const int* dst = ei + E_EDGES;

    k_wprep<<<64, 256, 0, stream>>>(Wl1, Wr1, Wl2, Wr2, Wt1, Wt2);
    k_hist<<<(E_EDGES + 255) / 256, 256, 0, stream>>>(dst, hist);
    k_scanA<<<NB, 256, 0, stream>>>(hist, bsum);
    k_scanB<<<1, 512, 0, stream>>>(bsum, boff, rowptr);
    k_scanC<<<NB, 256, 0, stream>>>(hist, boff, rowptr);
    k_fill2<<<NGRP * 640, 256, 0, stream>>>(src, dst, rowptr, cursor, csr);

    k_gemm1<<<(N_NODES + 63) / 64, 256, 0, stream>>>(x, Wt1, h1l, h1r);
    k_agg1<<<N_NODES / 4, 256, 0, stream>>>(rowptr, csr, h1l, h1r, b1);
    k_gemm2<<<(N_NODES + 63) / 64, 256, 0, stream>>>(h1r, Wt2, h2l, h2r);
    k_agg2<<<N_NODES / 4, 256, 0, stream>>>(rowptr, csr, h2l, h2r, b2, (float*)d_out);
}

// Round 6
// 388.443 us; speedup vs baseline: 2.3779x; 1.0845x over previous
//
#include <hip/hip_runtime.h>
#include <hip/hip_bf16.h>

#define N_NODES 100000
#define E_EDGES 1600000
#define IN_C 128
#define HID_C 64
#define OUT_C 40
#define NB 391        // ceil(N_NODES/256)
#define NGRP 8        // XCD count
#define RANGE (N_NODES / NGRP)   // 12500 exact

typedef unsigned short ushort_t;
typedef unsigned int uint_t;
typedef unsigned char uchar_t;
typedef __attribute__((ext_vector_type(8))) short bf16x8;
typedef __attribute__((ext_vector_type(4))) float f32x4;
typedef __attribute__((ext_vector_type(2))) float f32x2;

__device__ __forceinline__ float bfu2f(ushort_t u) {
    return __uint_as_float(((uint_t)u) << 16);
}
__device__ __forceinline__ ushort_t f2bfu(float f) {   // RNE
    uint_t u = __float_as_uint(f);
    return (ushort_t)((u + 0x7FFFu + ((u >> 16) & 1u)) >> 16);
}
__device__ __forceinline__ uchar_t f2fp8(float f) {    // e4m3 via HW cvt
    int p = __builtin_amdgcn_cvt_pk_fp8_f32(f, f, 0, false);
    return (uchar_t)(p & 0xff);
}

// ---------------------------------------------------------------- in-degree histogram (int)
__global__ void k_hist(const int* __restrict__ dst, int* __restrict__ hist) {
    int i = blockIdx.x * 256 + threadIdx.x;
    if (i < E_EDGES) atomicAdd(&hist[dst[i]], 1);
}

// ---------------------------------------------------------------- scan A: per-block sums
__global__ __launch_bounds__(256) void k_scanA(const int* __restrict__ hist, int* __restrict__ bsum) {
    __shared__ int tmp[256];
    int i = blockIdx.x * 256 + threadIdx.x;
    int v = (i < N_NODES) ? hist[i] : 0;
    tmp[threadIdx.x] = v;
    __syncthreads();
    for (int off = 128; off > 0; off >>= 1) {
        if (threadIdx.x < off) tmp[threadIdx.x] += tmp[threadIdx.x + off];
        __syncthreads();
    }
    if (threadIdx.x == 0) bsum[blockIdx.x] = tmp[0];
}

// ---------------------------------------------------------------- scan B: exclusive scan of block sums (1 block)
__global__ __launch_bounds__(512) void k_scanB(const int* __restrict__ bsum, int* __restrict__ boff,
                                               int* __restrict__ rowptr) {
    __shared__ int tmp[512];
    int t = threadIdx.x;
    int v = (t < NB) ? bsum[t] : 0;
    tmp[t] = v;
    __syncthreads();
    for (int off = 1; off < 512; off <<= 1) {
        int a = (t >= off) ? tmp[t - off] : 0;
        __syncthreads();
        tmp[t] += a;
        __syncthreads();
    }
    if (t < NB) boff[t] = tmp[t] - v;   // exclusive
    if (t == 0) rowptr[N_NODES] = E_EDGES;
}

// ---------------------------------------------------------------- scan C: rowptr[i] = boff[b] + exclusive-in-block
__global__ __launch_bounds__(256) void k_scanC(const int* __restrict__ hist, const int* __restrict__ boff,
                                               int* __restrict__ rowptr) {
    __shared__ int tmp[256];
    int i = blockIdx.x * 256 + threadIdx.x;
    int t = threadIdx.x;
    int v = (i < N_NODES) ? hist[i] : 0;
    tmp[t] = v;
    __syncthreads();
    for (int off = 1; off < 256; off <<= 1) {
        int a = (t >= off) ? tmp[t - off] : 0;
        __syncthreads();
        tmp[t] += a;
        __syncthreads();
    }
    if (i < N_NODES) rowptr[i] = boff[blockIdx.x] + tmp[t] - v;
}

// ---------------------------------------------------------------- fill CSR, XCD-range-partitioned
__global__ __launch_bounds__(256) void k_fill2(const int* __restrict__ src, const int* __restrict__ dst,
                                               const int* __restrict__ rowptr,
                                               int* __restrict__ cursor, int* __restrict__ csr) {
    int g = blockIdx.x & (NGRP - 1);
    int lo = g * RANGE, hi = lo + RANGE;
    int nchunk = gridDim.x >> 3;
    int stride = nchunk * 256;
    for (int i = (blockIdx.x >> 3) * 256 + threadIdx.x; i < E_EDGES; i += stride) {
        int d = dst[i];
        if (d >= lo && d < hi) {
            int s = src[i];
            int pos = atomicAdd(&cursor[d], 1);
            csr[rowptr[d] + pos] = s;
        }
    }
}

// ---------------------------------------------------------------- weight prep: bf16, transposed, l|r concatenated
__global__ __launch_bounds__(256) void k_wprep(const float* __restrict__ Wl1, const float* __restrict__ Wr1,
                                               const float* __restrict__ Wl2, const float* __restrict__ Wr2,
                                               ushort_t* __restrict__ Wt1, ushort_t* __restrict__ Wt2) {
    int i = blockIdx.x * 256 + threadIdx.x;
    if (i < 128 * 128) {
        int n = i >> 7, k = i & 127;
        float v = (n < 64) ? Wl1[k * 64 + n] : Wr1[k * 64 + (n - 64)];
        Wt1[n * 128 + k] = f2bfu(v);
    }
    if (i < 80 * 64) {
        int n = i >> 6, k = i & 63;
        float v = (n < 40) ? Wl2[k * 40 + n] : Wr2[k * 40 + (n - 40)];
        Wt2[n * 64 + k] = f2bfu(v);
    }
}

// ---------------------------------------------------------------- GEMM1 (MFMA): [h1l(fp8)|h1r(f32)] = x @ [Wl1|Wr1]
__global__ __launch_bounds__(256) void k_gemm1(const float* __restrict__ x,
                                               const ushort_t* __restrict__ Wt,  // [128][128] bf16
                                               uchar_t* __restrict__ h1l,
                                               float* __restrict__ h1r) {
    __shared__ ushort_t xs[64 * 136];
    __shared__ ushort_t wsm[128 * 136];
    const int t = threadIdx.x;
    const int row_base = blockIdx.x * 64;

    for (int i = t; i < 128 * 16; i += 256) {
        int n = i >> 4, seg = i & 15;
        uint4 v = *(const uint4*)(Wt + n * 128 + seg * 8);
        *(uint4*)(wsm + n * 136 + seg * 8) = v;
    }
    for (int i = t; i < 64 * 32; i += 256) {
        int row = i >> 5, seg = i & 31;
        int gr = row_base + row;
        float4 v = make_float4(0.f, 0.f, 0.f, 0.f);
        if (gr < N_NODES) v = *(const float4*)(x + (size_t)gr * IN_C + seg * 4);
        ushort4 u;
        u.x = f2bfu(v.x); u.y = f2bfu(v.y); u.z = f2bfu(v.z); u.w = f2bfu(v.w);
        *(ushort4*)(xs + row * 136 + seg * 4) = u;
    }
    __syncthreads();

    const int wv = t >> 6, lane = t & 63;
    const int m = lane & 15, quad = lane >> 4;
    const int m0 = wv * 16;

    bf16x8 a[4];
#pragma unroll
    for (int kk = 0; kk < 4; ++kk)
        a[kk] = *(const bf16x8*)(xs + (m0 + m) * 136 + kk * 32 + quad * 8);

    f32x4 acc[8];
#pragma unroll
    for (int nt = 0; nt < 8; ++nt) acc[nt] = (f32x4){0.f, 0.f, 0.f, 0.f};

#pragma unroll
    for (int nt = 0; nt < 8; ++nt) {
#pragma unroll
        for (int kk = 0; kk < 4; ++kk) {
            bf16x8 b = *(const bf16x8*)(wsm + (nt * 16 + m) * 136 + kk * 32 + quad * 8);
            acc[nt] = __builtin_amdgcn_mfma_f32_16x16x32_bf16(a[kk], b, acc[nt], 0, 0, 0);
        }
    }

    const int grow_base = row_base + m0 + quad * 4;
#pragma unroll
    for (int r = 0; r < 4; ++r) {
        int grow = grow_base + r;
        if (grow < N_NODES) {
#pragma unroll
            for (int nt = 0; nt < 4; ++nt)
                h1l[(size_t)grow * HID_C + nt * 16 + m] = f2fp8(acc[nt][r]);
#pragma unroll
            for (int nt = 4; nt < 8; ++nt)
                h1r[(size_t)grow * HID_C + (nt - 4) * 16 + m] = acc[nt][r];
        }
    }
}

// ---------------------------------------------------------------- agg1: gather fp8 h1l rows (64 B, 1 line), 8 edges/iter
// fused relu(mean + root + b1) -> h1r in place. One wave per dst row.
__global__ __launch_bounds__(256) void k_agg1(const int* __restrict__ rowptr, const int* __restrict__ csr,
                                              const uchar_t* __restrict__ h1l, float* __restrict__ h1r,
                                              const float* __restrict__ b1) {
    int wave = (blockIdx.x * 256 + threadIdx.x) >> 6;
    int lane = threadIdx.x & 63;
    if (wave >= N_NODES) return;
    int start = rowptr[wave];
    int end = rowptr[wave + 1];
    const int slot = lane >> 3;      // 0..7: edge slot
    const int part = lane & 7;       // 0..7: 8-channel chunk
    float acc[8] = {0.f, 0.f, 0.f, 0.f, 0.f, 0.f, 0.f, 0.f};

    for (int base = start; base < end; base += 8) {
        int e = base + slot;
        int ee = min(e, end - 1);
        int s = csr[ee];
        uint2 u = *(const uint2*)(h1l + (size_t)s * HID_C + part * 8);
        if (e >= end) { u.x = 0u; u.y = 0u; }
        f32x2 f;
        f = __builtin_amdgcn_cvt_pk_f32_fp8(u.x, false); acc[0] += f.x; acc[1] += f.y;
        f = __builtin_amdgcn_cvt_pk_f32_fp8(u.x, true);  acc[2] += f.x; acc[3] += f.y;
        f = __builtin_amdgcn_cvt_pk_f32_fp8(u.y, false); acc[4] += f.x; acc[5] += f.y;
        f = __builtin_amdgcn_cvt_pk_f32_fp8(u.y, true);  acc[6] += f.x; acc[7] += f.y;
    }
    // reduce across the 8 slots (lane bits 3,4,5)
#pragma unroll
    for (int off = 8; off <= 32; off <<= 1)
#pragma unroll
        for (int j = 0; j < 8; ++j)
            acc[j] += __shfl_xor(acc[j], off);

    if (slot == 0) {   // lanes 0..7 hold channels part*8 .. part*8+7
        float inv = 1.0f / fmaxf((float)(end - start), 1.0f);
        size_t base_i = (size_t)wave * HID_C + part * 8;
        float4 r0 = *(const float4*)(h1r + base_i);
        float4 r1 = *(const float4*)(h1r + base_i + 4);
        float4 bb0 = *(const float4*)(b1 + part * 8);
        float4 bb1 = *(const float4*)(b1 + part * 8 + 4);
        float4 o0, o1;
        o0.x = fmaxf(acc[0] * inv + r0.x + bb0.x, 0.f);
        o0.y = fmaxf(acc[1] * inv + r0.y + bb0.y, 0.f);
        o0.z = fmaxf(acc[2] * inv + r0.z + bb0.z, 0.f);
        o0.w = fmaxf(acc[3] * inv + r0.w + bb0.w, 0.f);
        o1.x = fmaxf(acc[4] * inv + r1.x + bb1.x, 0.f);
        o1.y = fmaxf(acc[5] * inv + r1.y + bb1.y, 0.f);
        o1.z = fmaxf(acc[6] * inv + r1.z + bb1.z, 0.f);
        o1.w = fmaxf(acc[7] * inv + r1.w + bb1.w, 0.f);
        *(float4*)(h1r + base_i) = o0;
        *(float4*)(h1r + base_i + 4) = o1;
    }
}

// ---------------------------------------------------------------- GEMM2 (MFMA): [h2l(fp8,stride64)|h2r(f32)] = hid @ [Wl2|Wr2]
__global__ __launch_bounds__(256) void k_gemm2(const float* __restrict__ hid,
                                               const ushort_t* __restrict__ Wt,  // [80][64] bf16
                                               uchar_t* __restrict__ h2l,
                                               float* __restrict__ h2r) {
    __shared__ ushort_t hs[64 * 72];
    __shared__ ushort_t wsm[80 * 72];
    const int t = threadIdx.x;
    const int row_base = blockIdx.x * 64;

    for (int i = t; i < 80 * 8; i += 256) {
        int n = i >> 3, seg = i & 7;
        uint4 v = *(const uint4*)(Wt + n * 64 + seg * 8);
        *(uint4*)(wsm + n * 72 + seg * 8) = v;
    }
    for (int i = t; i < 64 * 16; i += 256) {
        int row = i >> 4, seg = i & 15;
        int gr = row_base + row;
        float4 v = make_float4(0.f, 0.f, 0.f, 0.f);
        if (gr < N_NODES) v = *(const float4*)(hid + (size_t)gr * HID_C + seg * 4);
        ushort4 u;
        u.x = f2bfu(v.x); u.y = f2bfu(v.y); u.z = f2bfu(v.z); u.w = f2bfu(v.w);
        *(ushort4*)(hs + row * 72 + seg * 4) = u;
    }
    __syncthreads();

    const int wv = t >> 6, lane = t & 63;
    const int m = lane & 15, quad = lane >> 4;
    const int m0 = wv * 16;

    bf16x8 a[2];
#pragma unroll
    for (int kk = 0; kk < 2; ++kk)
        a[kk] = *(const bf16x8*)(hs + (m0 + m) * 72 + kk * 32 + quad * 8);

    f32x4 acc[5];
#pragma unroll
    for (int nt = 0; nt < 5; ++nt) acc[nt] = (f32x4){0.f, 0.f, 0.f, 0.f};

#pragma unroll
    for (int nt = 0; nt < 5; ++nt) {
#pragma unroll
        for (int kk = 0; kk < 2; ++kk) {
            bf16x8 b = *(const bf16x8*)(wsm + (nt * 16 + m) * 72 + kk * 32 + quad * 8);
            acc[nt] = __builtin_amdgcn_mfma_f32_16x16x32_bf16(a[kk], b, acc[nt], 0, 0, 0);
        }
    }

    const int grow_base = row_base + m0 + quad * 4;
#pragma unroll
    for (int r = 0; r < 4; ++r) {
        int grow = grow_base + r;
        if (grow < N_NODES) {
#pragma unroll
            for (int nt = 0; nt < 5; ++nt) {
                int col = nt * 16 + m;
                float v = acc[nt][r];
                if (col < OUT_C) h2l[(size_t)grow * 64 + col] = f2fp8(v);
                else             h2r[(size_t)grow * OUT_C + (col - OUT_C)] = v;
            }
        }
    }
}

// ---------------------------------------------------------------- agg2: gather fp8 h2l rows (40B in 64B stride, 1 line),
// 12 edges/iter; fused log_softmax(mean + root + b2). One wave per dst row.
__global__ __launch_bounds__(256) void k_agg2(const int* __restrict__ rowptr, const int* __restrict__ csr,
                                              const uchar_t* __restrict__ h2l, const float* __restrict__ h2r,
                                              const float* __restrict__ b2, float* __restrict__ out) {
    int wave = (blockIdx.x * 256 + threadIdx.x) >> 6;
    int lane = threadIdx.x & 63;
    if (wave >= N_NODES) return;
    int start = rowptr[wave];
    int end = rowptr[wave + 1];
    const int slot = lane / 5;       // 0..11 valid (lanes 60..63: slot 12, masked)
    const int part = lane - slot * 5;  // 0..4: 8-channel chunk
    float acc[8] = {0.f, 0.f, 0.f, 0.f, 0.f, 0.f, 0.f, 0.f};

    for (int base = start; base < end; base += 12) {
        int e = base + slot;
        bool ok = (slot < 12) && (e < end);
        int ee = min(e, end - 1);
        int s = csr[ee];
        uint2 u = *(const uint2*)(h2l + (size_t)s * 64 + part * 8);
        if (!ok) { u.x = 0u; u.y = 0u; }
        f32x2 f;
        f = __builtin_amdgcn_cvt_pk_f32_fp8(u.x, false); acc[0] += f.x; acc[1] += f.y;
        f = __builtin_amdgcn_cvt_pk_f32_fp8(u.x, true);  acc[2] += f.x; acc[3] += f.y;
        f = __builtin_amdgcn_cvt_pk_f32_fp8(u.y, false); acc[4] += f.x; acc[5] += f.y;
        f = __builtin_amdgcn_cvt_pk_f32_fp8(u.y, true);  acc[6] += f.x; acc[7] += f.y;
    }
    // tree-reduce 12 slots -> slot 0 (lanes 0..4)
    float tmp[8], tmp2[8];
#pragma unroll
    for (int j = 0; j < 8; ++j) tmp[j] = __shfl(acc[j], (lane + 30) & 63);
    if (lane < 30) {
#pragma unroll
        for (int j = 0; j < 8; ++j) acc[j] += tmp[j];
    }
#pragma unroll
    for (int j = 0; j < 8; ++j) tmp[j] = __shfl(acc[j], (lane + 15) & 63);
    if (lane < 15) {
#pragma unroll
        for (int j = 0; j < 8; ++j) acc[j] += tmp[j];
    }
#pragma unroll
    for (int j = 0; j < 8; ++j) {
        tmp[j] = __shfl(acc[j], (lane + 5) & 63);
        tmp2[j] = __shfl(acc[j], (lane + 10) & 63);
    }
    if (lane < 5) {
#pragma unroll
        for (int j = 0; j < 8; ++j) acc[j] += tmp[j] + tmp2[j];
    }

    // lanes 0..4 hold channels part*8 .. part*8+7 (part == lane here)
    bool fin = lane < 5;
    float inv = 1.0f / fmaxf((float)(end - start), 1.0f);
    float v[8];
    if (fin) {
        size_t base_i = (size_t)wave * OUT_C + lane * 8;
        float4 r0 = *(const float4*)(h2r + base_i);
        float4 r1 = *(const float4*)(h2r + base_i + 4);
        float4 bb0 = *(const float4*)(b2 + lane * 8);
        float4 bb1 = *(const float4*)(b2 + lane * 8 + 4);
        v[0] = acc[0] * inv + r0.x + bb0.x;
        v[1] = acc[1] * inv + r0.y + bb0.y;
        v[2] = acc[2] * inv + r0.z + bb0.z;
        v[3] = acc[3] * inv + r0.w + bb0.w;
        v[4] = acc[4] * inv + r1.x + bb1.x;
        v[5] = acc[5] * inv + r1.y + bb1.y;
        v[6] = acc[6] * inv + r1.z + bb1.z;
        v[7] = acc[7] * inv + r1.w + bb1.w;
    } else {
#pragma unroll
        for (int j = 0; j < 8; ++j) v[j] = -1e30f;
    }
    // softmax stats across lanes 0..7 (5..7 neutral)
    float pm = v[0];
#pragma unroll
    for (int j = 1; j < 8; ++j) pm = fmaxf(pm, v[j]);
#pragma unroll
    for (int off = 1; off <= 4; off <<= 1) pm = fmaxf(pm, __shfl_xor(pm, off));
    float es = 0.f;
#pragma unroll
    for (int j = 0; j < 8; ++j) es += expf(v[j] - pm);
#pragma unroll
    for (int off = 1; off <= 4; off <<= 1) es += __shfl_xor(es, off);
    float ls = logf(es);
    if (fin) {
        float4 o0 = make_float4(v[0] - pm - ls, v[1] - pm - ls, v[2] - pm - ls, v[3] - pm - ls);
        float4 o1 = make_float4(v[4] - pm - ls, v[5] - pm - ls, v[6] - pm - ls, v[7] - pm - ls);
        size_t base_o = (size_t)wave * OUT_C + lane * 8;
        *(float4*)(out + base_o) = o0;
        *(float4*)(out + base_o + 4) = o1;
    }
}

// ----------------------------------------------------------------
extern "C" void kernel_launch(void* const* d_in, const int* in_sizes, int n_in,
                              void* d_out, int out_size, void* d_ws, size_t ws_size,
                              hipStream_t stream) {
    const float* x   = (const float*)d_in[0];
    const int*   ei  = (const int*)d_in[1];
    const float* Wl1 = (const float*)d_in[2];
    const float* b1  = (const float*)d_in[3];
    const float* Wr1 = (const float*)d_in[4];
    const float* Wl2 = (const float*)d_in[5];
    const float* b2  = (const float*)d_in[6];
    const float* Wr2 = (const float*)d_in[7];

    // ws layout (4B units): hist | cursor | rowptr | bsum | boff | csr | [align16] |
    //   Wt1 bf16[128*128] | Wt2 bf16[80*64] | h1l fp8[N*64] | h1r f32[N*64] | h2l fp8[N*64] | h2r f32[N*40]
    size_t u = 0;
    int*      hist   = (int*)d_ws;             u += N_NODES;
    int*      cursor = (int*)d_ws + u;         u += N_NODES;
    int*      rowptr = (int*)d_ws + u;         u += N_NODES + 1;
    int*      bsum   = (int*)d_ws + u;         u += 512;
    int*      boff   = (int*)d_ws + u;         u += 512;
    int*      csr    = (int*)d_ws + u;         u += E_EDGES;
    u = (u + 3) & ~(size_t)3;                  // 16B align
    ushort_t* Wt1    = (ushort_t*)((int*)d_ws + u); u += 128 * 128 / 2;
    ushort_t* Wt2    = (ushort_t*)((int*)d_ws + u); u += 80 * 64 / 2;
    uchar_t*  h1l    = (uchar_t*)((int*)d_ws + u);  u += (size_t)N_NODES * HID_C / 4;
    float*    h1r    = (float*)d_ws + u;       u += (size_t)N_NODES * HID_C;
    uchar_t*  h2l    = (uchar_t*)((int*)d_ws + u);  u += (size_t)N_NODES * 64 / 4;
    float*    h2r    = (float*)d_ws + u;       u += (size_t)N_NODES * OUT_C;
    if (ws_size < u * 4) return;

    hipMemsetAsync(hist, 0, N_NODES * sizeof(int), stream);
    hipMemsetAsync(cursor, 0, N_NODES * sizeof(int), stream);

    const int* src = ei;
    const int* dst = ei + E_EDGES;

    k_wprep<<<64, 256, 0, stream>>>(Wl1, Wr1, Wl2, Wr2, Wt1, Wt2);
    k_hist<<<(E_EDGES + 255) / 256, 256, 0, stream>>>(dst, hist);
    k_scanA<<<NB, 256, 0, stream>>>(hist, bsum);
    k_scanB<<<1, 512, 0, stream>>>(bsum, boff, rowptr);
    k_scanC<<<NB, 256, 0, stream>>>(hist, boff, rowptr);
    k_fill2<<<NGRP * 640, 256, 0, stream>>>(src, dst, rowptr, cursor, csr);

    k_gemm1<<<(N_NODES + 63) / 64, 256, 0, stream>>>(x, Wt1, h1l, h1r);
    k_agg1<<<N_NODES / 4, 256, 0, stream>>>(rowptr, csr, h1l, h1r, b1);
    k_gemm2<<<(N_NODES + 63) / 64, 256, 0, stream>>>(h1r, Wt2, h2l, h2r);
    k_agg2<<<N_NODES / 4, 256, 0, stream>>>(rowptr, csr, h2l, h2r, b2, (float*)d_out);
}

// Round 7
// 278.855 us; speedup vs baseline: 3.3124x; 1.3930x over previous
//
#include <hip/hip_runtime.h>
#include <hip/hip_bf16.h>

#define N_NODES 100000
#define E_EDGES 1600000
#define IN_C 128
#define HID_C 64
#define OUT_C 40

#define NBUCK 196          // ceil(100000 / 512) buckets by dst>>9
#define BCAP 9216          // mean 8192 + 11 sigma
#define B1_EPT 16
#define B1_CHUNK (256 * B1_EPT)   // 4096 edges per block
#define B1_GRID ((E_EDGES + B1_CHUNK - 1) / B1_CHUNK)

typedef unsigned short ushort_t;
typedef unsigned int uint_t;
typedef unsigned char uchar_t;
typedef __attribute__((ext_vector_type(8))) short bf16x8;
typedef __attribute__((ext_vector_type(4))) float f32x4;
typedef __attribute__((ext_vector_type(2))) float f32x2;

__device__ __forceinline__ float bfu2f(ushort_t u) {
    return __uint_as_float(((uint_t)u) << 16);
}
__device__ __forceinline__ ushort_t f2bfu(float f) {   // RNE
    uint_t u = __float_as_uint(f);
    return (ushort_t)((u + 0x7FFFu + ((u >> 16) & 1u)) >> 16);
}
__device__ __forceinline__ uchar_t f2fp8(float f) {    // e4m3 via HW cvt
    int p = __builtin_amdgcn_cvt_pk_fp8_f32(f, f, 0, false);
    return (uchar_t)(p & 0xff);
}

// ---------------------------------------------------------------- bucketize edges by dst>>9
__global__ __launch_bounds__(256) void k_bucket(const int* __restrict__ src, const int* __restrict__ dst,
                                                int* __restrict__ bcur, int2* __restrict__ bucket) {
    __shared__ int cnt[NBUCK];
    __shared__ int base[NBUCK];
    const int t = threadIdx.x;
    const int e0 = blockIdx.x * B1_CHUNK;

    for (int i = t; i < NBUCK; i += 256) cnt[i] = 0;
    __syncthreads();

    int2 my[B1_EPT];
#pragma unroll
    for (int j = 0; j < B1_EPT; ++j) {
        int e = e0 + t + j * 256;
        if (e < E_EDGES) {
            my[j].x = src[e];
            my[j].y = dst[e];
            atomicAdd(&cnt[my[j].y >> 9], 1);
        } else {
            my[j].y = -1;
        }
    }
    __syncthreads();
    for (int i = t; i < NBUCK; i += 256) {
        base[i] = atomicAdd(&bcur[i], cnt[i]);
        cnt[i] = 0;
    }
    __syncthreads();
#pragma unroll
    for (int j = 0; j < B1_EPT; ++j) {
        if (my[j].y >= 0) {
            int b = my[j].y >> 9;
            int loc = atomicAdd(&cnt[b], 1);
            int pos = base[b] + loc;
            if (pos < BCAP) bucket[(size_t)b * BCAP + pos] = my[j];
        }
    }
}

// ---------------------------------------------------------------- exclusive scan of bucket sizes (1 block)
__global__ __launch_bounds__(256) void k_scanS(const int* __restrict__ bcur, int* __restrict__ bbase,
                                               int* __restrict__ rowptr) {
    __shared__ int tmp[256];
    int t = threadIdx.x;
    int v = (t < NBUCK) ? min(bcur[t], BCAP) : 0;
    tmp[t] = v;
    __syncthreads();
    for (int off = 1; off < 256; off <<= 1) {
        int a = (t >= off) ? tmp[t - off] : 0;
        __syncthreads();
        tmp[t] += a;
        __syncthreads();
    }
    if (t < NBUCK) bbase[t] = tmp[t] - v;
    if (t == 0) rowptr[N_NODES] = tmp[255];   // total kept edges (== E barring overflow)
}

// ---------------------------------------------------------------- per-bucket counting sort -> rowptr slice + csr slice
__global__ __launch_bounds__(256) void k_csr(const int2* __restrict__ bucket, const int* __restrict__ bcur,
                                             const int* __restrict__ bbase,
                                             int* __restrict__ rowptr, int* __restrict__ csr) {
    __shared__ int hist[512];
    __shared__ int sc[2][512];
    __shared__ int cur[512];
    __shared__ int csrbuf[BCAP];
    const int t = threadIdx.x;
    const int b = blockIdx.x;
    const int n0 = b << 9;
    const int nb = min(512, N_NODES - n0);
    const int sz = min(bcur[b], BCAP);
    const int cbase = bbase[b];
    const int2* bdata = bucket + (size_t)b * BCAP;

    for (int i = t; i < 512; i += 256) hist[i] = 0;
    __syncthreads();
    for (int i = t; i < sz; i += 256) {
        int2 e = bdata[i];
        atomicAdd(&hist[e.y - n0], 1);
    }
    __syncthreads();
    // inclusive scan of hist[512] (double buffer)
    for (int i = t; i < 512; i += 256) sc[0][i] = hist[i];
    __syncthreads();
    int pp = 0;
    for (int off = 1; off < 512; off <<= 1) {
        for (int i = t; i < 512; i += 256)
            sc[1 - pp][i] = sc[pp][i] + ((i >= off) ? sc[pp][i - off] : 0);
        __syncthreads();
        pp ^= 1;
    }
    for (int i = t; i < 512; i += 256) {
        int exc = sc[pp][i] - hist[i];
        cur[i] = exc;
        if (i < nb) rowptr[n0 + i] = cbase + exc;
    }
    __syncthreads();
    for (int i = t; i < sz; i += 256) {
        int2 e = bdata[i];
        int pos = atomicAdd(&cur[e.y - n0], 1);
        csrbuf[pos] = e.x;
    }
    __syncthreads();
    for (int i = t; i < sz; i += 256)
        csr[cbase + i] = csrbuf[i];
}

// ---------------------------------------------------------------- weight prep: bf16, transposed, l|r concatenated
__global__ __launch_bounds__(256) void k_wprep(const float* __restrict__ Wl1, const float* __restrict__ Wr1,
                                               const float* __restrict__ Wl2, const float* __restrict__ Wr2,
                                               ushort_t* __restrict__ Wt1, ushort_t* __restrict__ Wt2) {
    int i = blockIdx.x * 256 + threadIdx.x;
    if (i < 128 * 128) {
        int n = i >> 7, k = i & 127;
        float v = (n < 64) ? Wl1[k * 64 + n] : Wr1[k * 64 + (n - 64)];
        Wt1[n * 128 + k] = f2bfu(v);
    }
    if (i < 80 * 64) {
        int n = i >> 6, k = i & 63;
        float v = (n < 40) ? Wl2[k * 40 + n] : Wr2[k * 40 + (n - 40)];
        Wt2[n * 64 + k] = f2bfu(v);
    }
}

// ---------------------------------------------------------------- GEMM1 (MFMA): [h1l(fp8)|h1r(f32)] = x @ [Wl1|Wr1]
__global__ __launch_bounds__(256) void k_gemm1(const float* __restrict__ x,
                                               const ushort_t* __restrict__ Wt,  // [128][128] bf16
                                               uchar_t* __restrict__ h1l,
                                               float* __restrict__ h1r) {
    __shared__ ushort_t xs[64 * 136];
    __shared__ ushort_t wsm[128 * 136];
    const int t = threadIdx.x;
    const int row_base = blockIdx.x * 64;

    for (int i = t; i < 128 * 16; i += 256) {
        int n = i >> 4, seg = i & 15;
        uint4 v = *(const uint4*)(Wt + n * 128 + seg * 8);
        *(uint4*)(wsm + n * 136 + seg * 8) = v;
    }
    for (int i = t; i < 64 * 32; i += 256) {
        int row = i >> 5, seg = i & 31;
        int gr = row_base + row;
        float4 v = make_float4(0.f, 0.f, 0.f, 0.f);
        if (gr < N_NODES) v = *(const float4*)(x + (size_t)gr * IN_C + seg * 4);
        ushort4 u;
        u.x = f2bfu(v.x); u.y = f2bfu(v.y); u.z = f2bfu(v.z); u.w = f2bfu(v.w);
        *(ushort4*)(xs + row * 136 + seg * 4) = u;
    }
    __syncthreads();

    const int wv = t >> 6, lane = t & 63;
    const int m = lane & 15, quad = lane >> 4;
    const int m0 = wv * 16;

    bf16x8 a[4];
#pragma unroll
    for (int kk = 0; kk < 4; ++kk)
        a[kk] = *(const bf16x8*)(xs + (m0 + m) * 136 + kk * 32 + quad * 8);

    f32x4 acc[8];
#pragma unroll
    for (int nt = 0; nt < 8; ++nt) acc[nt] = (f32x4){0.f, 0.f, 0.f, 0.f};

#pragma unroll
    for (int nt = 0; nt < 8; ++nt) {
#pragma unroll
        for (int kk = 0; kk < 4; ++kk) {
            bf16x8 b = *(const bf16x8*)(wsm + (nt * 16 + m) * 136 + kk * 32 + quad * 8);
            acc[nt] = __builtin_amdgcn_mfma_f32_16x16x32_bf16(a[kk], b, acc[nt], 0, 0, 0);
        }
    }

    const int grow_base = row_base + m0 + quad * 4;
#pragma unroll
    for (int r = 0; r < 4; ++r) {
        int grow = grow_base + r;
        if (grow < N_NODES) {
#pragma unroll
            for (int nt = 0; nt < 4; ++nt)
                h1l[(size_t)grow * HID_C + nt * 16 + m] = f2fp8(acc[nt][r]);
#pragma unroll
            for (int nt = 4; nt < 8; ++nt)
                h1r[(size_t)grow * HID_C + (nt - 4) * 16 + m] = acc[nt][r];
        }
    }
}

// ---------------------------------------------------------------- agg1: gather fp8 h1l rows (64 B, 1 line), 8 edges/iter
__global__ __launch_bounds__(256) void k_agg1(const int* __restrict__ rowptr, const int* __restrict__ csr,
                                              const uchar_t* __restrict__ h1l, float* __restrict__ h1r,
                                              const float* __restrict__ b1) {
    int wave = (blockIdx.x * 256 + threadIdx.x) >> 6;
    int lane = threadIdx.x & 63;
    if (wave >= N_NODES) return;
    int start = rowptr[wave];
    int end = rowptr[wave + 1];
    const int slot = lane >> 3;      // 0..7: edge slot
    const int part = lane & 7;       // 0..7: 8-channel chunk
    float acc[8] = {0.f, 0.f, 0.f, 0.f, 0.f, 0.f, 0.f, 0.f};

    for (int base = start; base < end; base += 8) {
        int e = base + slot;
        int ee = min(e, end - 1);
        int s = csr[ee];
        uint2 u = *(const uint2*)(h1l + (size_t)s * HID_C + part * 8);
        if (e >= end) { u.x = 0u; u.y = 0u; }
        f32x2 f;
        f = __builtin_amdgcn_cvt_pk_f32_fp8(u.x, false); acc[0] += f.x; acc[1] += f.y;
        f = __builtin_amdgcn_cvt_pk_f32_fp8(u.x, true);  acc[2] += f.x; acc[3] += f.y;
        f = __builtin_amdgcn_cvt_pk_f32_fp8(u.y, false); acc[4] += f.x; acc[5] += f.y;
        f = __builtin_amdgcn_cvt_pk_f32_fp8(u.y, true);  acc[6] += f.x; acc[7] += f.y;
    }
#pragma unroll
    for (int off = 8; off <= 32; off <<= 1)
#pragma unroll
        for (int j = 0; j < 8; ++j)
            acc[j] += __shfl_xor(acc[j], off);

    if (slot == 0) {   // lanes 0..7 hold channels part*8 .. part*8+7
        float inv = 1.0f / fmaxf((float)(end - start), 1.0f);
        size_t base_i = (size_t)wave * HID_C + part * 8;
        float4 r0 = *(const float4*)(h1r + base_i);
        float4 r1 = *(const float4*)(h1r + base_i + 4);
        float4 bb0 = *(const float4*)(b1 + part * 8);
        float4 bb1 = *(const float4*)(b1 + part * 8 + 4);
        float4 o0, o1;
        o0.x = fmaxf(acc[0] * inv + r0.x + bb0.x, 0.f);
        o0.y = fmaxf(acc[1] * inv + r0.y + bb0.y, 0.f);
        o0.z = fmaxf(acc[2] * inv + r0.z + bb0.z, 0.f);
        o0.w = fmaxf(acc[3] * inv + r0.w + bb0.w, 0.f);
        o1.x = fmaxf(acc[4] * inv + r1.x + bb1.x, 0.f);
        o1.y = fmaxf(acc[5] * inv + r1.y + bb1.y, 0.f);
        o1.z = fmaxf(acc[6] * inv + r1.z + bb1.z, 0.f);
        o1.w = fmaxf(acc[7] * inv + r1.w + bb1.w, 0.f);
        *(float4*)(h1r + base_i) = o0;
        *(float4*)(h1r + base_i + 4) = o1;
    }
}

// ---------------------------------------------------------------- GEMM2 (MFMA): [h2l(fp8,stride64)|h2r(f32)] = hid @ [Wl2|Wr2]
__global__ __launch_bounds__(256) void k_gemm2(const float* __restrict__ hid,
                                               const ushort_t* __restrict__ Wt,  // [80][64] bf16
                                               uchar_t* __restrict__ h2l,
                                               float* __restrict__ h2r) {
    __shared__ ushort_t hs[64 * 72];
    __shared__ ushort_t wsm[80 * 72];
    const int t = threadIdx.x;
    const int row_base = blockIdx.x * 64;

    for (int i = t; i < 80 * 8; i += 256) {
        int n = i >> 3, seg = i & 7;
        uint4 v = *(const uint4*)(Wt + n * 64 + seg * 8);
        *(uint4*)(wsm + n * 72 + seg * 8) = v;
    }
    for (int i = t; i < 64 * 16; i += 256) {
        int row = i >> 4, seg = i & 15;
        int gr = row_base + row;
        float4 v = make_float4(0.f, 0.f, 0.f, 0.f);
        if (gr < N_NODES) v = *(const float4*)(hid + (size_t)gr * HID_C + seg * 4);
        ushort4 u;
        u.x = f2bfu(v.x); u.y = f2bfu(v.y); u.z = f2bfu(v.z); u.w = f2bfu(v.w);
        *(ushort4*)(hs + row * 72 + seg * 4) = u;
    }
    __syncthreads();

    const int wv = t >> 6, lane = t & 63;
    const int m = lane & 15, quad = lane >> 4;
    const int m0 = wv * 16;

    bf16x8 a[2];
#pragma unroll
    for (int kk = 0; kk < 2; ++kk)
        a[kk] = *(const bf16x8*)(hs + (m0 + m) * 72 + kk * 32 + quad * 8);

    f32x4 acc[5];
#pragma unroll
    for (int nt = 0; nt < 5; ++nt) acc[nt] = (f32x4){0.f, 0.f, 0.f, 0.f};

#pragma unroll
    for (int nt = 0; nt < 5; ++nt) {
#pragma unroll
        for (int kk = 0; kk < 2; ++kk) {
            bf16x8 b = *(const bf16x8*)(wsm + (nt * 16 + m) * 72 + kk * 32 + quad * 8);
            acc[nt] = __builtin_amdgcn_mfma_f32_16x16x32_bf16(a[kk], b, acc[nt], 0, 0, 0);
        }
    }

    const int grow_base = row_base + m0 + quad * 4;
#pragma unroll
    for (int r = 0; r < 4; ++r) {
        int grow = grow_base + r;
        if (grow < N_NODES) {
#pragma unroll
            for (int nt = 0; nt < 5; ++nt) {
                int col = nt * 16 + m;
                float v = acc[nt][r];
                if (col < OUT_C) h2l[(size_t)grow * 64 + col] = f2fp8(v);
                else             h2r[(size_t)grow * OUT_C + (col - OUT_C)] = v;
            }
        }
    }
}

// ---------------------------------------------------------------- agg2: gather fp8 h2l rows, 12 edges/iter + log_softmax
__global__ __launch_bounds__(256) void k_agg2(const int* __restrict__ rowptr, const int* __restrict__ csr,
                                              const uchar_t* __restrict__ h2l, const float* __restrict__ h2r,
                                              const float* __restrict__ b2, float* __restrict__ out) {
    int wave = (blockIdx.x * 256 + threadIdx.x) >> 6;
    int lane = threadIdx.x & 63;
    if (wave >= N_NODES) return;
    int start = rowptr[wave];
    int end = rowptr[wave + 1];
    const int slot = lane / 5;       // 0..11 valid
    const int part = lane - slot * 5;  // 0..4
    float acc[8] = {0.f, 0.f, 0.f, 0.f, 0.f, 0.f, 0.f, 0.f};

    for (int base = start; base < end; base += 12) {
        int e = base + slot;
        bool ok = (slot < 12) && (e < end);
        int ee = min(e, end - 1);
        int s = csr[ee];
        uint2 u = *(const uint2*)(h2l + (size_t)s * 64 + part * 8);
        if (!ok) { u.x = 0u; u.y = 0u; }
        f32x2 f;
        f = __builtin_amdgcn_cvt_pk_f32_fp8(u.x, false); acc[0] += f.x; acc[1] += f.y;
        f = __builtin_amdgcn_cvt_pk_f32_fp8(u.x, true);  acc[2] += f.x; acc[3] += f.y;
        f = __builtin_amdgcn_cvt_pk_f32_fp8(u.y, false); acc[4] += f.x; acc[5] += f.y;
        f = __builtin_amdgcn_cvt_pk_f32_fp8(u.y, true);  acc[6] += f.x; acc[7] += f.y;
    }
    float tmp[8], tmp2[8];
#pragma unroll
    for (int j = 0; j < 8; ++j) tmp[j] = __shfl(acc[j], (lane + 30) & 63);
    if (lane < 30) {
#pragma unroll
        for (int j = 0; j < 8; ++j) acc[j] += tmp[j];
    }
#pragma unroll
    for (int j = 0; j < 8; ++j) tmp[j] = __shfl(acc[j], (lane + 15) & 63);
    if (lane < 15) {
#pragma unroll
        for (int j = 0; j < 8; ++j) acc[j] += tmp[j];
    }
#pragma unroll
    for (int j = 0; j < 8; ++j) {
        tmp[j] = __shfl(acc[j], (lane + 5) & 63);
        tmp2[j] = __shfl(acc[j], (lane + 10) & 63);
    }
    if (lane < 5) {
#pragma unroll
        for (int j = 0; j < 8; ++j) acc[j] += tmp[j] + tmp2[j];
    }

    bool fin = lane < 5;
    float inv = 1.0f / fmaxf((float)(end - start), 1.0f);
    float v[8];
    if (fin) {
        size_t base_i = (size_t)wave * OUT_C + lane * 8;
        float4 r0 = *(const float4*)(h2r + base_i);
        float4 r1 = *(const float4*)(h2r + base_i + 4);
        float4 bb0 = *(const float4*)(b2 + lane * 8);
        float4 bb1 = *(const float4*)(b2 + lane * 8 + 4);
        v[0] = acc[0] * inv + r0.x + bb0.x;
        v[1] = acc[1] * inv + r0.y + bb0.y;
        v[2] = acc[2] * inv + r0.z + bb0.z;
        v[3] = acc[3] * inv + r0.w + bb0.w;
        v[4] = acc[4] * inv + r1.x + bb1.x;
        v[5] = acc[5] * inv + r1.y + bb1.y;
        v[6] = acc[6] * inv + r1.z + bb1.z;
        v[7] = acc[7] * inv + r1.w + bb1.w;
    } else {
#pragma unroll
        for (int j = 0; j < 8; ++j) v[j] = -1e30f;
    }
    float pm = v[0];
#pragma unroll
    for (int j = 1; j < 8; ++j) pm = fmaxf(pm, v[j]);
#pragma unroll
    for (int off = 1; off <= 4; off <<= 1) pm = fmaxf(pm, __shfl_xor(pm, off));
    float es = 0.f;
#pragma unroll
    for (int j = 0; j < 8; ++j) es += expf(v[j] - pm);
#pragma unroll
    for (int off = 1; off <= 4; off <<= 1) es += __shfl_xor(es, off);
    float ls = logf(es);
    if (fin) {
        float4 o0 = make_float4(v[0] - pm - ls, v[1] - pm - ls, v[2] - pm - ls, v[3] - pm - ls);
        float4 o1 = make_float4(v[4] - pm - ls, v[5] - pm - ls, v[6] - pm - ls, v[7] - pm - ls);
        size_t base_o = (size_t)wave * OUT_C + lane * 8;
        *(float4*)(out + base_o) = o0;
        *(float4*)(out + base_o + 4) = o1;
    }
}

// ----------------------------------------------------------------
extern "C" void kernel_launch(void* const* d_in, const int* in_sizes, int n_in,
                              void* d_out, int out_size, void* d_ws, size_t ws_size,
                              hipStream_t stream) {
    const float* x   = (const float*)d_in[0];
    const int*   ei  = (const int*)d_in[1];
    const float* Wl1 = (const float*)d_in[2];
    const float* b1  = (const float*)d_in[3];
    const float* Wr1 = (const float*)d_in[4];
    const float* Wl2 = (const float*)d_in[5];
    const float* b2  = (const float*)d_in[6];
    const float* Wr2 = (const float*)d_in[7];

    // ws layout (4B units): bucket int2[196*9216] | bcur | bbase | rowptr[N+1] | csr[E] |
    //   [align16] | Wt1 bf16[128*128] | Wt2 bf16[80*64] | h1l fp8[N*64] | h1r f32[N*64] |
    //   h2l fp8[N*64] | h2r f32[N*40]
    size_t u = 0;
    int2*     bucket = (int2*)d_ws;            u += (size_t)NBUCK * BCAP * 2;
    int*      bcur   = (int*)d_ws + u;         u += NBUCK;
    int*      bbase  = (int*)d_ws + u;         u += NBUCK + 4;
    int*      rowptr = (int*)d_ws + u;         u += N_NODES + 1;
    int*      csr    = (int*)d_ws + u;         u += E_EDGES;
    u = (u + 3) & ~(size_t)3;                  // 16B align
    ushort_t* Wt1    = (ushort_t*)((int*)d_ws + u); u += 128 * 128 / 2;
    ushort_t* Wt2    = (ushort_t*)((int*)d_ws + u); u += 80 * 64 / 2;
    uchar_t*  h1l    = (uchar_t*)((int*)d_ws + u);  u += (size_t)N_NODES * HID_C / 4;
    float*    h1r    = (float*)d_ws + u;       u += (size_t)N_NODES * HID_C;
    uchar_t*  h2l    = (uchar_t*)((int*)d_ws + u);  u += (size_t)N_NODES * 64 / 4;
    float*    h2r    = (float*)d_ws + u;       u += (size_t)N_NODES * OUT_C;
    if (ws_size < u * 4) return;

    hipMemsetAsync(bcur, 0, NBUCK * sizeof(int), stream);

    const int* src = ei;
    const int* dst = ei + E_EDGES;

    k_wprep<<<64, 256, 0, stream>>>(Wl1, Wr1, Wl2, Wr2, Wt1, Wt2);
    k_bucket<<<B1_GRID, 256, 0, stream>>>(src, dst, bcur, bucket);
    k_scanS<<<1, 256, 0, stream>>>(bcur, bbase, rowptr);
    k_csr<<<NBUCK, 256, 0, stream>>>(bucket, bcur, bbase, rowptr, csr);

    k_gemm1<<<(N_NODES + 63) / 64, 256, 0, stream>>>(x, Wt1, h1l, h1r);
    k_agg1<<<N_NODES / 4, 256, 0, stream>>>(rowptr, csr, h1l, h1r, b1);
    k_gemm2<<<(N_NODES + 63) / 64, 256, 0, stream>>>(h1r, Wt2, h2l, h2r);
    k_agg2<<<N_NODES / 4, 256, 0, stream>>>(rowptr, csr, h2l, h2r, b2, (float*)d_out);
}